// Round 1
// baseline (2266.121 us; speedup 1.0000x reference)
//
#include <hip/hip_runtime.h>
#include <hip/hip_fp16.h>
#include <stdint.h>

#define B_ROWS 4096
#define D_IN   1024
#define H_HID  16384
#define K_TOP  32

typedef __attribute__((ext_vector_type(8))) _Float16 half8;
typedef __attribute__((ext_vector_type(4))) float    f32x4;

// ---------------- helpers ----------------

// Split fp32 into f16 hi + f16 lo*2^-11.  Values with |x| < 2^-14 (f16 min
// normal) go entirely into the (scaled) lo part so no meaningful magnitude
// ever depends on MFMA subnormal-input behavior.
__device__ __forceinline__ void split_f16_val(float x, ushort& hi, ushort& lo) {
  float hf = 0.0f;
  ushort hb = 0;
  if (fabsf(x) >= 0x1p-14f) {
    __half hh = __float2half(x);
    hb = __half_as_ushort(hh);
    hf = __half2float(hh);
  }
  float r = (x - hf) * 2048.0f;   // exact pow2 scale
  lo = __half_as_ushort(__float2half(r));
  hi = hb;
}

__device__ __forceinline__ void gload_lds16(const void* g, void* l) {
  __builtin_amdgcn_global_load_lds(
      (const __attribute__((address_space(1))) void*)g,
      (__attribute__((address_space(3))) void*)l, 16, 0, 0);
}

// ---------------- split kernels ----------------

__global__ __launch_bounds__(256) void split_a_kernel(const float* __restrict__ x,
                                                      ushort* __restrict__ hi,
                                                      ushort* __restrict__ lo) {
  const int t = blockIdx.x * 256 + threadIdx.x;
  const int base = t * 4;
  float4 v = *reinterpret_cast<const float4*>(x + base);
  ushort4 h, l;
  split_f16_val(v.x, h.x, l.x);
  split_f16_val(v.y, h.y, l.y);
  split_f16_val(v.z, h.z, l.z);
  split_f16_val(v.w, h.w, l.w);
  *reinterpret_cast<ushort4*>(hi + base) = h;
  *reinterpret_cast<ushort4*>(lo + base) = l;
}

// W [D_IN, H_HID] f32  ->  hiT/loT [H_HID, D_IN] f16 bits (transposed, split)
__global__ __launch_bounds__(256) void split_wt_kernel(const float* __restrict__ W,
                                                       ushort* __restrict__ hiT,
                                                       ushort* __restrict__ loT) {
  __shared__ float tile[32][33];
  const int c0 = blockIdx.x * 32;  // H columns
  const int r0 = blockIdx.y * 32;  // D rows
  const int tx = threadIdx.x;      // 0..31
  const int ty = threadIdx.y;      // 0..7
#pragma unroll
  for (int i = 0; i < 32; i += 8)
    tile[ty + i][tx] = W[(size_t)(r0 + ty + i) * H_HID + c0 + tx];
  __syncthreads();
#pragma unroll
  for (int i = 0; i < 32; i += 8) {
    float v = tile[tx][ty + i];   // = W[r0+tx][c0+ty+i]
    ushort hb, lb;
    split_f16_val(v, hb, lb);
    size_t o = (size_t)(c0 + ty + i) * D_IN + r0 + tx;
    hiT[o] = hb;
    loT[o] = lb;
  }
}

// ---------------- encoder GEMM ----------------
// H = relu(X @ W + b).  A: [B_ROWS, D_IN] f16-bits (hi/lo), B: [H_HID, D_IN]
// f16-bits transposed (hi/lo).  Segments: Ah*Bl' + Al'*Bh, scale 2^-11, + Ah*Bh.
// 128x128 tile, BK=32, 4 waves each computing 64x64 via 4x4 of 16x16x32 MFMA.
__global__ __launch_bounds__(256) void gemm_enc(const ushort* __restrict__ Ah,
                                                const ushort* __restrict__ Al,
                                                const ushort* __restrict__ Bh,
                                                const ushort* __restrict__ Bl,
                                                const float* __restrict__ bias,
                                                float* __restrict__ Hout) {
  __shared__ ushort ldsA[128 * 32];
  __shared__ ushort ldsB[128 * 32];
  const int tid  = threadIdx.x;
  const int wid  = tid >> 6;
  const int lane = tid & 63;
  const int tm   = blockIdx.x & 31;   // 32 M-tiles
  const int tn   = blockIdx.x >> 5;   // 128 N-tiles
  const int wm   = (wid & 1) * 64;
  const int wn   = (wid >> 1) * 64;

  f32x4 acc[4][4];
#pragma unroll
  for (int i = 0; i < 4; ++i)
#pragma unroll
    for (int j = 0; j < 4; ++j) {
      f32x4 z = {0.f, 0.f, 0.f, 0.f};
      acc[i][j] = z;
    }

  const int rowA  = tm * 128;
  const int rowB  = tn * 128;
  const int srow  = lane >> 2;        // 0..15
  const int skoff = (lane & 3) * 8;   // f16 elems

  const ushort* Aseg[3] = {Ah, Al, Ah};
  const ushort* Bseg[3] = {Bl, Bh, Bh};

#pragma unroll 1
  for (int seg = 0; seg < 3; ++seg) {
    const ushort* Ap = Aseg[seg];
    const ushort* Bp = Bseg[seg];
#pragma unroll 1
    for (int ks = 0; ks < D_IN / 32; ++ks) {
      const int k0 = ks * 32;
      __syncthreads();
#pragma unroll
      for (int q = 0; q < 2; ++q) {
        const int c = q * 4 + wid;           // chunk 0..7 (16 rows each)
        const int r = c * 16 + srow;
        gload_lds16(Ap + (size_t)(rowA + r) * D_IN + k0 + skoff, &ldsA[c * 512]);
        gload_lds16(Bp + (size_t)(rowB + r) * D_IN + k0 + skoff, &ldsB[c * 512]);
      }
      __syncthreads();
      half8 af[4], bfv[4];
#pragma unroll
      for (int i = 0; i < 4; ++i) {
        const int r = wm + i * 16 + (lane & 15);
        af[i] = *reinterpret_cast<const half8*>(&ldsA[r * 32 + (lane >> 4) * 8]);
      }
#pragma unroll
      for (int j = 0; j < 4; ++j) {
        const int r = wn + j * 16 + (lane & 15);
        bfv[j] = *reinterpret_cast<const half8*>(&ldsB[r * 32 + (lane >> 4) * 8]);
      }
#pragma unroll
      for (int i = 0; i < 4; ++i)
#pragma unroll
        for (int j = 0; j < 4; ++j)
          acc[i][j] = __builtin_amdgcn_mfma_f32_16x16x32_f16(af[i], bfv[j], acc[i][j], 0, 0, 0);
    }
    if (seg == 1) {   // lo-terms done: scale by 2^-11 before hi*hi segment
#pragma unroll
      for (int i = 0; i < 4; ++i)
#pragma unroll
        for (int j = 0; j < 4; ++j)
#pragma unroll
          for (int p = 0; p < 4; ++p)
            acc[i][j][p] *= 0x1p-11f;
    }
  }

  // epilogue: +bias, relu, store dense h (f32) into the latent output region
  const int ccol = lane & 15;
  const int crow = (lane >> 4) * 4;
#pragma unroll
  for (int j = 0; j < 4; ++j) {
    const int col = tn * 128 + wn + j * 16 + ccol;
    const float bv = bias[col];
#pragma unroll
    for (int i = 0; i < 4; ++i) {
      const int row0 = tm * 128 + wm + i * 16 + crow;
#pragma unroll
      for (int p = 0; p < 4; ++p) {
        float v = acc[i][j][p] + bv;
        Hout[(size_t)(row0 + p) * H_HID + col] = fmaxf(v, 0.0f);
      }
    }
  }
}

// ---------------- top-K sparsify (in place) ----------------
// One block per row.  Exact 32nd-largest via 4-pass 8-bit radix select on the
// float bits (all values >= 0 post-relu -> bits are monotone).  Ties at the
// threshold are taken lowest-index-first (matches jax.lax.top_k).
__global__ __launch_bounds__(256) void topk_kernel(float* __restrict__ latent,
                                                   float* __restrict__ cvals,
                                                   int* __restrict__ cidx) {
  __shared__ float    sh[H_HID];   // 64 KB
  __shared__ uint32_t hist[256];
  __shared__ uint32_t sscan[256];
  __shared__ int      sh_digit;
  __shared__ int      sel_cnt;
  __shared__ int      sel_idx[K_TOP];

  const int tid = threadIdx.x;
  const int row = blockIdx.x;
  float* rowp = latent + (size_t)row * H_HID;

  for (int i = tid; i < H_HID / 4; i += 256)
    reinterpret_cast<float4*>(sh)[i] = reinterpret_cast<const float4*>(rowp)[i];
  __syncthreads();

  uint32_t prefix = 0;
  int need = K_TOP;
#pragma unroll 1
  for (int pass = 0; pass < 4; ++pass) {
    const int shift = 24 - pass * 8;
    hist[tid] = 0;
    __syncthreads();
    const uint32_t pmask = (pass == 0) ? 0u : (0xFFFFFFFFu << (shift + 8));
    for (int i = tid; i < H_HID; i += 256) {
      uint32_t key = __float_as_uint(sh[i]);
      if ((key & pmask) == prefix)
        atomicAdd(&hist[(key >> shift) & 255], 1u);
    }
    __syncthreads();
    sscan[tid] = hist[tid];
    __syncthreads();
    for (int off = 1; off < 256; off <<= 1) {
      uint32_t v = (tid + off < 256) ? sscan[tid + off] : 0u;
      __syncthreads();
      sscan[tid] += v;
      __syncthreads();
    }
    if (sscan[tid] >= (uint32_t)need && (tid == 255 || sscan[tid + 1] < (uint32_t)need))
      sh_digit = tid;
    __syncthreads();
    const int d = sh_digit;
    if (d < 255) need -= (int)sscan[d + 1];
    prefix |= ((uint32_t)d) << shift;
    __syncthreads();
  }

  const float T = __uint_as_float(prefix);  // exact kth-largest value
  const int n_eq = need;                    // #values == T to take (>=1)

  if (tid < 64) {  // wave 0: first n_eq equal values in index order
    int taken = 0;
    for (int base = 0; base < H_HID && taken < n_eq; base += 64) {
      bool eq = (sh[base + tid] == T);
      unsigned long long m = __ballot(eq);
      int below = __popcll(m & ((1ull << tid) - 1ull));
      if (eq && taken + below < n_eq) sel_idx[taken + below] = base + tid;
      taken += __popcll(m);
    }
  }
  if (tid == 0) sel_cnt = 0;
  __syncthreads();

  for (int i4 = tid; i4 < H_HID / 4; i4 += 256) {
    float4 v = reinterpret_cast<const float4*>(sh)[i4];
    float vs[4] = {v.x, v.y, v.z, v.w};
    float os[4];
#pragma unroll
    for (int c = 0; c < 4; ++c) {
      const bool g = vs[c] > T;
      os[c] = g ? vs[c] : 0.0f;
      if (g) {
        int p = atomicAdd(&sel_cnt, 1);
        cvals[row * K_TOP + p] = vs[c];
        cidx[row * K_TOP + p]  = i4 * 4 + c;
      }
    }
    reinterpret_cast<float4*>(rowp)[i4] = make_float4(os[0], os[1], os[2], os[3]);
  }
  __syncthreads();
  const int c_gt = K_TOP - n_eq;
  if (tid < n_eq) {
    const int j = sel_idx[tid];
    rowp[j] = T;
    cvals[row * K_TOP + c_gt + tid] = T;
    cidx[row * K_TOP + c_gt + tid]  = j;
  }
}

// ---------------- sparse decoder ----------------
// recon[row,:] = b + sum_k val_k * Wdec[idx_k,:]   (one block per row)
__global__ __launch_bounds__(256) void decode_kernel(const float* __restrict__ cvals,
                                                     const int* __restrict__ cidx,
                                                     const float* __restrict__ Wdec,
                                                     const float* __restrict__ bias,
                                                     float* __restrict__ recon) {
  __shared__ float sv[K_TOP];
  __shared__ int   si[K_TOP];
  const int tid = threadIdx.x;
  const int row = blockIdx.x;
  if (tid < K_TOP) {
    sv[tid] = cvals[row * K_TOP + tid];
    si[tid] = cidx[row * K_TOP + tid];
  }
  __syncthreads();
  const float4 b4 = reinterpret_cast<const float4*>(bias)[tid];
  float ax = b4.x, ay = b4.y, az = b4.z, aw = b4.w;
#pragma unroll 1
  for (int k = 0; k < K_TOP; ++k) {
    const float v = sv[k];
    const float4 w = reinterpret_cast<const float4*>(Wdec + (size_t)si[k] * D_IN)[tid];
    ax = fmaf(v, w.x, ax);
    ay = fmaf(v, w.y, ay);
    az = fmaf(v, w.z, az);
    aw = fmaf(v, w.w, aw);
  }
  reinterpret_cast<float4*>(recon + (size_t)row * D_IN)[tid] = make_float4(ax, ay, az, aw);
}

// ---------------- launch ----------------

extern "C" void kernel_launch(void* const* d_in, const int* in_sizes, int n_in,
                              void* d_out, int out_size, void* d_ws, size_t ws_size,
                              hipStream_t stream) {
  (void)in_sizes; (void)n_in; (void)out_size; (void)ws_size;
  const float* Xv     = (const float*)d_in[0];
  const float* Xt     = (const float*)d_in[1];
  const float* Wv_enc = (const float*)d_in[2];
  const float* bv_enc = (const float*)d_in[3];
  const float* Wt_enc = (const float*)d_in[4];
  const float* bt_enc = (const float*)d_in[5];
  const float* Wv_dec = (const float*)d_in[6];
  const float* bv_dec = (const float*)d_in[7];
  const float* Wt_dec = (const float*)d_in[8];
  const float* bt_dec = (const float*)d_in[9];

  float* out      = (float*)d_out;
  float* recon_v  = out;
  float* recon_t  = out + (size_t)B_ROWS * D_IN;
  float* latent_v = out + 2ull * B_ROWS * D_IN;
  float* latent_t = latent_v + (size_t)B_ROWS * H_HID;

  // workspace layout (bytes): 4 A-splits (8MB ea) | 4 B-splits (32MB ea) | compact lists
  char* ws = (char*)d_ws;
  const size_t szA = (size_t)B_ROWS * D_IN;   // elements
  const size_t szB = (size_t)H_HID * D_IN;    // elements
  ushort* Ah_v = (ushort*)ws;
  ushort* Al_v = Ah_v + szA;
  ushort* Ah_t = Al_v + szA;
  ushort* Al_t = Ah_t + szA;
  ushort* Bh_v = Al_t + szA;
  ushort* Bl_v = Bh_v + szB;
  ushort* Bh_t = Bl_v + szB;
  ushort* Bl_t = Bh_t + szB;
  float*  cvals_v = (float*)(Bl_t + szB);
  float*  cvals_t = cvals_v + (size_t)B_ROWS * K_TOP;
  int*    cidx_v  = (int*)(cvals_t + (size_t)B_ROWS * K_TOP);
  int*    cidx_t  = cidx_v + (size_t)B_ROWS * K_TOP;

  // 1) precision splits (A: elementwise; W: transpose+split)
  split_a_kernel<<<B_ROWS * D_IN / 1024, 256, 0, stream>>>(Xv, Ah_v, Al_v);
  split_a_kernel<<<B_ROWS * D_IN / 1024, 256, 0, stream>>>(Xt, Ah_t, Al_t);
  dim3 tg(H_HID / 32, D_IN / 32);
  split_wt_kernel<<<tg, dim3(32, 8), 0, stream>>>(Wv_enc, Bh_v, Bl_v);
  split_wt_kernel<<<tg, dim3(32, 8), 0, stream>>>(Wt_enc, Bh_t, Bl_t);

  // 2) encoder GEMMs (dense h written into latent regions of d_out)
  gemm_enc<<<(B_ROWS / 128) * (H_HID / 128), 256, 0, stream>>>(Ah_v, Al_v, Bh_v, Bl_v, bv_enc, latent_v);
  gemm_enc<<<(B_ROWS / 128) * (H_HID / 128), 256, 0, stream>>>(Ah_t, Al_t, Bh_t, Bl_t, bt_enc, latent_t);

  // 3) exact top-32 sparsify in place + compact lists
  topk_kernel<<<B_ROWS, 256, 0, stream>>>(latent_v, cvals_v, cidx_v);
  topk_kernel<<<B_ROWS, 256, 0, stream>>>(latent_t, cvals_t, cidx_t);

  // 4) sparse decoders
  decode_kernel<<<B_ROWS, 256, 0, stream>>>(cvals_v, cidx_v, Wv_dec, bv_dec, recon_v);
  decode_kernel<<<B_ROWS, 256, 0, stream>>>(cvals_t, cidx_t, Wt_dec, bt_dec, recon_t);
}

// Round 2
// 1650.168 us; speedup vs baseline: 1.3733x; 1.3733x over previous
//
#include <hip/hip_runtime.h>
#include <hip/hip_fp16.h>
#include <stdint.h>

#define B_ROWS 4096
#define D_IN   1024
#define H_HID  16384
#define K_TOP  32

typedef __attribute__((ext_vector_type(8))) _Float16 half8;
typedef __attribute__((ext_vector_type(4))) float    f32x4;

// ---------------- helpers ----------------

// Split fp32 into f16 hi + f16 lo*2^-11.  Values with |x| < 2^-14 (f16 min
// normal) go entirely into the (scaled) lo part so no meaningful magnitude
// ever depends on MFMA subnormal-input behavior.
__device__ __forceinline__ void split_f16_val(float x, ushort& hi, ushort& lo) {
  float hf = 0.0f;
  ushort hb = 0;
  if (fabsf(x) >= 0x1p-14f) {
    __half hh = __float2half(x);
    hb = __half_as_ushort(hh);
    hf = __half2float(hh);
  }
  float r = (x - hf) * 2048.0f;   // exact pow2 scale
  lo = __half_as_ushort(__float2half(r));
  hi = hb;
}

__device__ __forceinline__ void gload_lds16(const void* g, void* l) {
  __builtin_amdgcn_global_load_lds(
      (const __attribute__((address_space(1))) void*)g,
      (__attribute__((address_space(3))) void*)l, 16, 0, 0);
}

// ---------------- split kernels ----------------

__global__ __launch_bounds__(256) void split_a_kernel(const float* __restrict__ x,
                                                      ushort* __restrict__ hi,
                                                      ushort* __restrict__ lo) {
  const int t = blockIdx.x * 256 + threadIdx.x;
  const int base = t * 4;
  float4 v = *reinterpret_cast<const float4*>(x + base);
  ushort4 h, l;
  split_f16_val(v.x, h.x, l.x);
  split_f16_val(v.y, h.y, l.y);
  split_f16_val(v.z, h.z, l.z);
  split_f16_val(v.w, h.w, l.w);
  *reinterpret_cast<ushort4*>(hi + base) = h;
  *reinterpret_cast<ushort4*>(lo + base) = l;
}

// W [D_IN, H_HID] f32  ->  hiT/loT [H_HID, D_IN] f16 bits (transposed, split)
__global__ __launch_bounds__(256) void split_wt_kernel(const float* __restrict__ W,
                                                       ushort* __restrict__ hiT,
                                                       ushort* __restrict__ loT) {
  __shared__ float tile[32][33];
  const int c0 = blockIdx.x * 32;  // H columns
  const int r0 = blockIdx.y * 32;  // D rows
  const int tx = threadIdx.x;      // 0..31
  const int ty = threadIdx.y;      // 0..7
#pragma unroll
  for (int i = 0; i < 32; i += 8)
    tile[ty + i][tx] = W[(size_t)(r0 + ty + i) * H_HID + c0 + tx];
  __syncthreads();
#pragma unroll
  for (int i = 0; i < 32; i += 8) {
    float v = tile[tx][ty + i];   // = W[r0+tx][c0+ty+i]
    ushort hb, lb;
    split_f16_val(v, hb, lb);
    size_t o = (size_t)(c0 + ty + i) * D_IN + r0 + tx;
    hiT[o] = hb;
    loT[o] = lb;
  }
}

// ---------------- encoder GEMM ----------------
// H = relu(X @ W + b).  A: [B_ROWS, D_IN] f16-bits (hi/lo), B: [H_HID, D_IN]
// f16-bits transposed (hi/lo).  Segments: Ah*Bl' + Al'*Bh, scale 2^-11, + Ah*Bh.
// 128x128 tile, BK=32, 4 waves each computing 64x64 via 4x4 of 16x16x32 MFMA.
__global__ __launch_bounds__(256) void gemm_enc(const ushort* __restrict__ Ah,
                                                const ushort* __restrict__ Al,
                                                const ushort* __restrict__ Bh,
                                                const ushort* __restrict__ Bl,
                                                const float* __restrict__ bias,
                                                float* __restrict__ Hout) {
  __shared__ ushort ldsA[128 * 32];
  __shared__ ushort ldsB[128 * 32];
  const int tid  = threadIdx.x;
  const int wid  = tid >> 6;
  const int lane = tid & 63;
  // bijective XCD swizzle: 4096 blocks, 8 XCDs -> each XCD gets a contiguous
  // 512-block chunk = a 16-wide tn slab (B-panel stays hot in its L2).
  const int bid  = (blockIdx.x & 7) * (4096 / 8) + (blockIdx.x >> 3);
  const int tm   = bid & 31;   // 32 M-tiles
  const int tn   = bid >> 5;   // 128 N-tiles
  const int wm   = (wid & 1) * 64;
  const int wn   = (wid >> 1) * 64;

  f32x4 acc[4][4];
#pragma unroll
  for (int i = 0; i < 4; ++i)
#pragma unroll
    for (int j = 0; j < 4; ++j) {
      f32x4 z = {0.f, 0.f, 0.f, 0.f};
      acc[i][j] = z;
    }

  const int rowA  = tm * 128;
  const int rowB  = tn * 128;
  const int srow  = lane >> 2;        // 0..15
  const int skoff = (lane & 3) * 8;   // f16 elems

  const ushort* Aseg[3] = {Ah, Al, Ah};
  const ushort* Bseg[3] = {Bl, Bh, Bh};

#pragma unroll 1
  for (int seg = 0; seg < 3; ++seg) {
    const ushort* Ap = Aseg[seg];
    const ushort* Bp = Bseg[seg];
#pragma unroll 1
    for (int ks = 0; ks < D_IN / 32; ++ks) {
      const int k0 = ks * 32;
      __syncthreads();
#pragma unroll
      for (int q = 0; q < 2; ++q) {
        const int c = q * 4 + wid;           // chunk 0..7 (16 rows each)
        const int r = c * 16 + srow;
        gload_lds16(Ap + (size_t)(rowA + r) * D_IN + k0 + skoff, &ldsA[c * 512]);
        gload_lds16(Bp + (size_t)(rowB + r) * D_IN + k0 + skoff, &ldsB[c * 512]);
      }
      __syncthreads();
      half8 af[4], bfv[4];
#pragma unroll
      for (int i = 0; i < 4; ++i) {
        const int r = wm + i * 16 + (lane & 15);
        af[i] = *reinterpret_cast<const half8*>(&ldsA[r * 32 + (lane >> 4) * 8]);
      }
#pragma unroll
      for (int j = 0; j < 4; ++j) {
        const int r = wn + j * 16 + (lane & 15);
        bfv[j] = *reinterpret_cast<const half8*>(&ldsB[r * 32 + (lane >> 4) * 8]);
      }
#pragma unroll
      for (int i = 0; i < 4; ++i)
#pragma unroll
        for (int j = 0; j < 4; ++j)
          acc[i][j] = __builtin_amdgcn_mfma_f32_16x16x32_f16(af[i], bfv[j], acc[i][j], 0, 0, 0);
    }
    if (seg == 1) {   // lo-terms done: scale by 2^-11 before hi*hi segment
#pragma unroll
      for (int i = 0; i < 4; ++i)
#pragma unroll
        for (int j = 0; j < 4; ++j)
#pragma unroll
          for (int p = 0; p < 4; ++p)
            acc[i][j][p] *= 0x1p-11f;
    }
  }

  // epilogue: +bias, relu, store dense h (f32) into the latent output region
  const int ccol = lane & 15;
  const int crow = (lane >> 4) * 4;
#pragma unroll
  for (int j = 0; j < 4; ++j) {
    const int col = tn * 128 + wn + j * 16 + ccol;
    const float bv = bias[col];
#pragma unroll
    for (int i = 0; i < 4; ++i) {
      const int row0 = tm * 128 + wm + i * 16 + crow;
#pragma unroll
      for (int p = 0; p < 4; ++p) {
        float v = acc[i][j][p] + bv;
        Hout[(size_t)(row0 + p) * H_HID + col] = fmaxf(v, 0.0f);
      }
    }
  }
}

// ---------------- top-K sparsify (in place) ----------------
// One block (512 thr) per row.  Exact 32nd-largest positive via 11-bit radix
// histogram (zeros SKIPPED - they can't be top-32 unless <32 positives, which
// is special-cased).  Usually 1 histogram pass -> compact <=512 candidates ->
// exact (value desc, index asc) rank = jax.lax.top_k tie-break.  Bit-exact.
#define TK_THREADS 512
#define TK_CAP     512

__global__ __launch_bounds__(TK_THREADS) void topk_kernel(float* __restrict__ latent,
                                                          float* __restrict__ cvals,
                                                          int* __restrict__ cidx) {
  __shared__ float    sh[H_HID];        // 64 KB row stage
  __shared__ uint32_t hist[2048];       // 8 KB; reused after select as cand/bitmap
  __shared__ uint32_t chunkS[TK_THREADS];
  __shared__ uint32_t sh_d, sh_cnt, sh_above;
  __shared__ int      s_special;
  __shared__ int      s_ndef, s_ncand;

  const int tid = threadIdx.x;
  const int row = blockIdx.x;
  float* rowp = latent + (size_t)row * H_HID;

  for (int i = tid; i < H_HID / 4; i += TK_THREADS)
    reinterpret_cast<float4*>(sh)[i] = reinterpret_cast<const float4*>(rowp)[i];
  __syncthreads();

  uint32_t prefix = 0, pmask = 0;
  uint32_t loB = 1, hiB = 1;            // special-case defaults: all positives definite
  int need = K_TOP;
  int special = 0;

#pragma unroll 1
  for (int level = 0; level < 3; ++level) {
    const int shift = (level == 0) ? 20 : (level == 1) ? 9 : 0;
    const int nbins = (level == 2) ? 512 : 2048;
    for (int b = tid; b < nbins; b += TK_THREADS) hist[b] = 0;
    __syncthreads();
    for (int i4 = tid; i4 < H_HID / 4; i4 += TK_THREADS) {
      float4 v = reinterpret_cast<const float4*>(sh)[i4];
      const float vs[4] = {v.x, v.y, v.z, v.w};
#pragma unroll
      for (int c = 0; c < 4; ++c) {
        uint32_t key = __float_as_uint(vs[c]);
        if (key != 0u && (key & pmask) == prefix)
          atomicAdd(&hist[(key >> shift) & (nbins - 1)], 1u);
      }
    }
    __syncthreads();
    const int cpt = nbins / TK_THREADS;  // 4 or 1 bins per thread
    uint32_t cs = 0;
#pragma unroll
    for (int c = 0; c < 4; ++c)
      if (c < cpt) cs += hist[tid * cpt + c];
    chunkS[tid] = cs;
    __syncthreads();
    for (int off = 1; off < TK_THREADS; off <<= 1) {
      uint32_t v = (tid + off < TK_THREADS) ? chunkS[tid + off] : 0u;
      __syncthreads();
      chunkS[tid] += v;
      __syncthreads();
    }
    if (level == 0 && tid == 0) s_special = (chunkS[0] <= (uint32_t)K_TOP);
    __syncthreads();
    if (level == 0 && s_special) { special = 1; break; }
    // find threshold bin d: suffix(d) >= need > suffix(d+1)
    {
      uint32_t cum = (tid + 1 < TK_THREADS) ? chunkS[tid + 1] : 0u;
#pragma unroll
      for (int c = 3; c >= 0; --c) {
        if (c < cpt) {
          const int b = tid * cpt + c;
          const uint32_t nxt = cum;
          cum += hist[b];
          if (cum >= (uint32_t)need && nxt < (uint32_t)need) {
            sh_d = (uint32_t)b; sh_cnt = hist[b]; sh_above = nxt;
          }
        }
      }
    }
    __syncthreads();
    const uint32_t d = sh_d, cnt = sh_cnt, above = sh_above;
    need -= (int)above;
    prefix |= d << shift;
    pmask  |= (uint32_t)(nbins - 1) << shift;
    loB = prefix;
    hiB = prefix + (1u << shift);
    if (cnt <= TK_CAP || level == 2) break;
  }
  const int r = special ? 0 : need;     // to take from candidate bucket

  // reuse hist space: cand lists + bitmap
  float*    cand_val = reinterpret_cast<float*>(hist);  // [512]
  int*      cand_idx = reinterpret_cast<int*>(hist + 512);
  uint32_t* bitmap   = hist + 1024;                     // [512] = 16384 bits
  __syncthreads();
  if (tid < 512) bitmap[tid] = 0u;
  if (tid == 0) { s_ndef = 0; s_ncand = 0; }
  __syncthreads();

  // compact pass: definite (key >= hiB) straight to output list; bucket
  // members [loB,hiB) to candidate list.
  for (int i4 = tid; i4 < H_HID / 4; i4 += TK_THREADS) {
    float4 v = reinterpret_cast<const float4*>(sh)[i4];
    const float vs[4] = {v.x, v.y, v.z, v.w};
#pragma unroll
    for (int c = 0; c < 4; ++c) {
      const uint32_t key = __float_as_uint(vs[c]);
      if (key == 0u) continue;
      const int i = i4 * 4 + c;
      if (key >= hiB) {
        const int p = atomicAdd(&s_ndef, 1);
        cvals[row * K_TOP + p] = vs[c];
        cidx[row * K_TOP + p]  = i;
        atomicOr(&bitmap[i >> 5], 1u << (i & 31));
      } else if (key >= loB) {
        const int p = atomicAdd(&s_ncand, 1);
        if (p < TK_CAP) { cand_val[p] = vs[c]; cand_idx[p] = i; }
      }
    }
  }
  __syncthreads();
  const int ndef = s_ndef, ncand = s_ncand;

  if (r > 0) {
    if (ncand <= TK_CAP) {
      // exact rank among candidates: value desc, index asc (jax tie-break)
      if (tid < ncand) {
        const float vi = cand_val[tid];
        const int   ii = cand_idx[tid];
        int rank = 0;
        for (int j = 0; j < ncand; ++j) {
          const float vj = cand_val[j];
          const int   ij = cand_idx[j];
          rank += (vj > vi) || (vj == vi && ij < ii);
        }
        if (rank < r) {
          cvals[row * K_TOP + ndef + rank] = vi;
          cidx[row * K_TOP + ndef + rank]  = ii;
          atomicOr(&bitmap[ii >> 5], 1u << (ii & 31));
        }
      }
    } else {
      // overflow => level-2 exit, all candidate keys identical: take lowest
      // indices first via wave-0 ballot scan.
      if (tid < 64) {
        int taken = 0;
        for (int base = 0; base < H_HID && taken < r; base += 64) {
          const uint32_t key = __float_as_uint(sh[base + tid]);
          const bool eq = (key >= loB && key < hiB);
          const unsigned long long m = __ballot(eq);
          const int below = __popcll(m & ((1ull << tid) - 1ull));
          if (eq && taken + below < r) {
            const int slot = ndef + taken + below;
            cvals[row * K_TOP + slot] = sh[base + tid];
            cidx[row * K_TOP + slot]  = base + tid;
            atomicOr(&bitmap[(base + tid) >> 5], 1u << ((base + tid) & 31));
          }
          taken += __popcll(m);
        }
      }
    }
  }
  // pad (only when <32 positives in the row)
  if (tid >= ndef + r && tid < K_TOP) {
    cvals[row * K_TOP + tid] = 0.0f;
    cidx[row * K_TOP + tid]  = 0;
  }
  __syncthreads();

  // write pass: keep selected, zero the rest
  for (int i4 = tid; i4 < H_HID / 4; i4 += TK_THREADS) {
    float4 v = reinterpret_cast<const float4*>(sh)[i4];
    const int i0 = i4 * 4;
    const uint32_t bm = bitmap[i0 >> 5];
    float4 o;
    o.x = ((bm >> ((i0 + 0) & 31)) & 1u) ? v.x : 0.0f;
    o.y = ((bm >> ((i0 + 1) & 31)) & 1u) ? v.y : 0.0f;
    o.z = ((bm >> ((i0 + 2) & 31)) & 1u) ? v.z : 0.0f;
    o.w = ((bm >> ((i0 + 3) & 31)) & 1u) ? v.w : 0.0f;
    reinterpret_cast<float4*>(rowp)[i4] = o;
  }
}

// ---------------- sparse decoder ----------------
// recon[row,:] = b + sum_k val_k * Wdec[idx_k,:]   (one block per row)
__global__ __launch_bounds__(256) void decode_kernel(const float* __restrict__ cvals,
                                                     const int* __restrict__ cidx,
                                                     const float* __restrict__ Wdec,
                                                     const float* __restrict__ bias,
                                                     float* __restrict__ recon) {
  __shared__ float sv[K_TOP];
  __shared__ int   si[K_TOP];
  const int tid = threadIdx.x;
  const int row = blockIdx.x;
  if (tid < K_TOP) {
    sv[tid] = cvals[row * K_TOP + tid];
    si[tid] = cidx[row * K_TOP + tid];
  }
  __syncthreads();
  const float4 b4 = reinterpret_cast<const float4*>(bias)[tid];
  float ax = b4.x, ay = b4.y, az = b4.z, aw = b4.w;
#pragma unroll 1
  for (int k = 0; k < K_TOP; ++k) {
    const float v = sv[k];
    const float4 w = reinterpret_cast<const float4*>(Wdec + (size_t)si[k] * D_IN)[tid];
    ax = fmaf(v, w.x, ax);
    ay = fmaf(v, w.y, ay);
    az = fmaf(v, w.z, az);
    aw = fmaf(v, w.w, aw);
  }
  reinterpret_cast<float4*>(recon + (size_t)row * D_IN)[tid] = make_float4(ax, ay, az, aw);
}

// ---------------- launch ----------------

extern "C" void kernel_launch(void* const* d_in, const int* in_sizes, int n_in,
                              void* d_out, int out_size, void* d_ws, size_t ws_size,
                              hipStream_t stream) {
  (void)in_sizes; (void)n_in; (void)out_size; (void)ws_size;
  const float* Xv     = (const float*)d_in[0];
  const float* Xt     = (const float*)d_in[1];
  const float* Wv_enc = (const float*)d_in[2];
  const float* bv_enc = (const float*)d_in[3];
  const float* Wt_enc = (const float*)d_in[4];
  const float* bt_enc = (const float*)d_in[5];
  const float* Wv_dec = (const float*)d_in[6];
  const float* bv_dec = (const float*)d_in[7];
  const float* Wt_dec = (const float*)d_in[8];
  const float* bt_dec = (const float*)d_in[9];

  float* out      = (float*)d_out;
  float* recon_v  = out;
  float* recon_t  = out + (size_t)B_ROWS * D_IN;
  float* latent_v = out + 2ull * B_ROWS * D_IN;
  float* latent_t = latent_v + (size_t)B_ROWS * H_HID;

  // workspace layout: 4 A-splits | 4 B-splits | compact lists
  char* ws = (char*)d_ws;
  const size_t szA = (size_t)B_ROWS * D_IN;   // elements
  const size_t szB = (size_t)H_HID * D_IN;    // elements
  ushort* Ah_v = (ushort*)ws;
  ushort* Al_v = Ah_v + szA;
  ushort* Ah_t = Al_v + szA;
  ushort* Al_t = Ah_t + szA;
  ushort* Bh_v = Al_t + szA;
  ushort* Bl_v = Bh_v + szB;
  ushort* Bh_t = Bl_v + szB;
  ushort* Bl_t = Bh_t + szB;
  float*  cvals_v = (float*)(Bl_t + szB);
  float*  cvals_t = cvals_v + (size_t)B_ROWS * K_TOP;
  int*    cidx_v  = (int*)(cvals_t + (size_t)B_ROWS * K_TOP);
  int*    cidx_t  = cidx_v + (size_t)B_ROWS * K_TOP;

  // 1) precision splits
  split_a_kernel<<<B_ROWS * D_IN / 1024, 256, 0, stream>>>(Xv, Ah_v, Al_v);
  split_a_kernel<<<B_ROWS * D_IN / 1024, 256, 0, stream>>>(Xt, Ah_t, Al_t);
  dim3 tg(H_HID / 32, D_IN / 32);
  split_wt_kernel<<<tg, dim3(32, 8), 0, stream>>>(Wv_enc, Bh_v, Bl_v);
  split_wt_kernel<<<tg, dim3(32, 8), 0, stream>>>(Wt_enc, Bh_t, Bl_t);

  // 2) encoder GEMMs (dense h written into latent regions of d_out)
  gemm_enc<<<(B_ROWS / 128) * (H_HID / 128), 256, 0, stream>>>(Ah_v, Al_v, Bh_v, Bl_v, bv_enc, latent_v);
  gemm_enc<<<(B_ROWS / 128) * (H_HID / 128), 256, 0, stream>>>(Ah_t, Al_t, Bh_t, Bl_t, bt_enc, latent_t);

  // 3) exact top-32 sparsify in place + compact lists
  topk_kernel<<<B_ROWS, TK_THREADS, 0, stream>>>(latent_v, cvals_v, cidx_v);
  topk_kernel<<<B_ROWS, TK_THREADS, 0, stream>>>(latent_t, cvals_t, cidx_t);

  // 4) sparse decoders
  decode_kernel<<<B_ROWS, 256, 0, stream>>>(cvals_v, cidx_v, Wv_dec, bv_dec, recon_v);
  decode_kernel<<<B_ROWS, 256, 0, stream>>>(cvals_t, cidx_t, Wt_dec, bt_dec, recon_t);
}

// Round 3
// 1305.238 us; speedup vs baseline: 1.7362x; 1.2643x over previous
//
#include <hip/hip_runtime.h>
#include <hip/hip_fp16.h>
#include <stdint.h>

#define B_ROWS 4096
#define D_IN   1024
#define H_HID  16384
#define K_TOP  32

typedef __attribute__((ext_vector_type(8))) _Float16 half8;
typedef __attribute__((ext_vector_type(4))) float    f32x4;

// ---------------- helpers ----------------

__device__ __forceinline__ void split_f16_val(float x, ushort& hi, ushort& lo) {
  float hf = 0.0f;
  ushort hb = 0;
  if (fabsf(x) >= 0x1p-14f) {
    __half hh = __float2half(x);
    hb = __half_as_ushort(hh);
    hf = __half2float(hh);
  }
  float r = (x - hf) * 2048.0f;   // exact pow2 scale
  lo = __half_as_ushort(__float2half(r));
  hi = hb;
}

__device__ __forceinline__ void gload_lds16(const void* g, void* l) {
  __builtin_amdgcn_global_load_lds(
      (const __attribute__((address_space(1))) void*)g,
      (__attribute__((address_space(3))) void*)l, 16, 0, 0);
}

// ---------------- split kernels ----------------

__global__ __launch_bounds__(256) void split_a_kernel(const float* __restrict__ x,
                                                      ushort* __restrict__ hi,
                                                      ushort* __restrict__ lo) {
  const int t = blockIdx.x * 256 + threadIdx.x;
  const int base = t * 4;
  float4 v = *reinterpret_cast<const float4*>(x + base);
  ushort4 h, l;
  split_f16_val(v.x, h.x, l.x);
  split_f16_val(v.y, h.y, l.y);
  split_f16_val(v.z, h.z, l.z);
  split_f16_val(v.w, h.w, l.w);
  *reinterpret_cast<ushort4*>(hi + base) = h;
  *reinterpret_cast<ushort4*>(lo + base) = l;
}

// W [D_IN, H_HID] f32 -> hiT/loT [H_HID, D_IN] f16 bits (transposed, split)
__global__ __launch_bounds__(256) void split_wt_kernel(const float* __restrict__ W,
                                                       ushort* __restrict__ hiT,
                                                       ushort* __restrict__ loT) {
  __shared__ float tile[32][33];
  const int c0 = blockIdx.x * 32;
  const int r0 = blockIdx.y * 32;
  const int tx = threadIdx.x;
  const int ty = threadIdx.y;
#pragma unroll
  for (int i = 0; i < 32; i += 8)
    tile[ty + i][tx] = W[(size_t)(r0 + ty + i) * H_HID + c0 + tx];
  __syncthreads();
#pragma unroll
  for (int i = 0; i < 32; i += 8) {
    float v = tile[tx][ty + i];
    ushort hb, lb;
    split_f16_val(v, hb, lb);
    size_t o = (size_t)(c0 + ty + i) * D_IN + r0 + tx;
    hiT[o] = hb;
    loT[o] = lb;
  }
}

// ---------------- encoder GEMM: 256x256 tile, 8-phase pipelined ----------------
// H = relu(X @ W + b) via split-f16 3-segment virtual-K GEMM:
//   segs: [Ah*Bl | Al*Bh] * 2^-11  +  [Ah*Bh]   (scale inserted after tile 31)
// BM=BN=256, BK=64, 8 waves (2Mx4N), per-wave 128x64 out = acc[8][4].
// LDS: 128KB double buffer (A 32KB + B 32KB per buf), dynamic.
// T2: XOR-swizzle (ushort idx ^ (lane&7)<<3) on ds_read; gload source is
//     inverse-swizzled so LDS dest stays lane-linear (rule 21).
// T3/T4: per-phase 2x global_load_lds, counted vmcnt(4)@ph2, vmcnt(2)@ph4.
// T5: setprio(1) around each 16-MFMA cluster.
#define NTILES 48   // 3 segments x (1024/64)

__global__ __launch_bounds__(512, 2) void gemm_enc_8ph(const ushort* __restrict__ Ah,
                                                       const ushort* __restrict__ Al,
                                                       const ushort* __restrict__ Bh,
                                                       const ushort* __restrict__ Bl,
                                                       const float* __restrict__ bias,
                                                       float* __restrict__ Hout) {
  extern __shared__ ushort smem[];   // [2][32768]: buf*32768, B-half at +16384
  const int tid  = threadIdx.x;
  const int wid  = tid >> 6;
  const int lane = tid & 63;
  const int wr   = wid >> 2;        // 0..1  (M half)
  const int wc   = wid & 3;         // 0..3  (N quarter)
  const int tm   = blockIdx.x & 15;
  const int tn   = blockIdx.x >> 4;
  const int rowA0 = tm * 256;
  const int rowB0 = tn * 256;

  // staging geometry: one quarter (64 rows x 64 K) per 8-wave gload; this
  // wave covers rows [wid*8, wid*8+8), lane covers 16B unit (lane&7) of a row
  const int st_row = wid * 8 + (lane >> 3);               // 0..63 in quarter
  const int st_lin = lane & 7;                            // linear 16B unit
  const int st_src = (lane & 7) ^ ((lane >> 3) & 7);      // inverse-swizzled
  // fragment geometry
  const int fr   = lane & 15;
  const int fk   = lane >> 4;                             // 0..3
  const int swz8 = (lane & 7) << 3;                       // ushort-idx XOR

  f32x4 acc[8][4];
#pragma unroll
  for (int i = 0; i < 8; ++i)
#pragma unroll
    for (int j = 0; j < 4; ++j) {
      f32x4 z = {0.f, 0.f, 0.f, 0.f};
      acc[i][j] = z;
    }
  half8 a[4][2], b[4][2];

#define DS_A(MH)                                                            \
  _Pragma("unroll") for (int m = 0; m < 4; ++m)                             \
  _Pragma("unroll") for (int k = 0; k < 2; ++k) {                           \
    const int r = wr * 128 + ((MH) * 4 + m) * 16 + fr;                      \
    const int idx = (r * 64 + k * 32 + fk * 8) ^ swz8;                      \
    a[m][k] = *reinterpret_cast<const half8*>(Acur + idx);                  \
  }
#define DS_B(NH)                                                            \
  _Pragma("unroll") for (int n = 0; n < 2; ++n)                             \
  _Pragma("unroll") for (int k = 0; k < 2; ++k) {                           \
    const int r = wc * 64 + ((NH) * 2 + n) * 16 + fr;                       \
    const int idx = (r * 64 + k * 32 + fk * 8) ^ swz8;                      \
    b[(NH) * 2 + n][k] = *reinterpret_cast<const half8*>(Bcur + idx);       \
  }
#define MFMA_PH(MH, NH)                                                     \
  __builtin_amdgcn_s_setprio(1);                                            \
  _Pragma("unroll") for (int m = 0; m < 4; ++m)                             \
  _Pragma("unroll") for (int n = 0; n < 2; ++n)                             \
  _Pragma("unroll") for (int k = 0; k < 2; ++k)                             \
    acc[(MH) * 4 + m][(NH) * 2 + n] = __builtin_amdgcn_mfma_f32_16x16x32_f16( \
        a[m][k], b[(NH) * 2 + n][k], acc[(MH) * 4 + m][(NH) * 2 + n], 0, 0, 0); \
  __builtin_amdgcn_s_setprio(0);
#define STAGE_A(Q)                                                          \
  gload_lds16(As + (size_t)(rowA0 + (Q) * 64 + st_row) * 1024 + k0 + st_src * 8, \
              Lnxt + ((Q) * 64 + st_row) * 64 + st_lin * 8)
#define STAGE_B(Q)                                                          \
  gload_lds16(Bs + (size_t)(rowB0 + (Q) * 64 + st_row) * 1024 + k0 + st_src * 8, \
              Lnxt + 16384 + ((Q) * 64 + st_row) * 64 + st_lin * 8)
#define BAR() __builtin_amdgcn_s_barrier()

  // prologue: stage tile 0 into buf0.  Order: Bq0..3, Aq0, Aq2, Aq1, Aq3.
  const ushort* As = Ah;
  const ushort* Bs = Bl;
  int k0 = 0;
  ushort* Lnxt = smem;
  STAGE_B(0); STAGE_B(1); STAGE_B(2); STAGE_B(3);
  STAGE_A(0); STAGE_A(2); STAGE_A(1); STAGE_A(3);
  asm volatile("s_waitcnt vmcnt(2)" ::: "memory");
  BAR();

#pragma unroll 1
  for (int t = 0; t < NTILES - 1; ++t) {
    const int cur = t & 1;
    const ushort* Acur = smem + cur * 32768;
    const ushort* Bcur = Acur + 16384;
    Lnxt = smem + (cur ^ 1) * 32768;
    const int tt = t + 1;
    const int sg = tt >> 4;
    k0 = (tt & 15) << 6;
    As = (sg == 1) ? Al : Ah;
    Bs = (sg == 0) ? Bl : Bh;

    // phase 1: A-half0 + B nrep0-1 reads; stage Bq0,Bq1
    DS_A(0); DS_B(0);
    STAGE_B(0); STAGE_B(1);
    BAR();
    MFMA_PH(0, 0);
    BAR();
    // phase 2: B nrep2-3 reads; stage Bq2,Bq3; wait prev-ph4 quarters
    DS_B(1);
    STAGE_B(2); STAGE_B(3);
    BAR();
    MFMA_PH(0, 1);
    asm volatile("s_waitcnt vmcnt(4)" ::: "memory");
    BAR();
    // phase 3: A-half1 reads; stage Aq0,Aq2
    DS_A(1);
    STAGE_A(0); STAGE_A(2);
    BAR();
    MFMA_PH(1, 0);
    BAR();
    // phase 4: all-resident; stage Aq1,Aq3; boundary wait (ph1-3 issued done)
    STAGE_A(1); STAGE_A(3);
    BAR();
    MFMA_PH(1, 1);
    asm volatile("s_waitcnt vmcnt(2)" ::: "memory");
    BAR();

    if (t == 31) {   // lo-segments done: scale before hi*hi segment
#pragma unroll
      for (int i = 0; i < 8; ++i)
#pragma unroll
        for (int j = 0; j < 4; ++j)
#pragma unroll
          for (int p = 0; p < 4; ++p)
            acc[i][j][p] *= 0x1p-11f;
    }
  }

  // epilogue tile 47 (no staging)
  {
    const ushort* Acur = smem + ((NTILES - 1) & 1) * 32768;
    const ushort* Bcur = Acur + 16384;
    DS_A(0); DS_B(0);
    BAR();
    MFMA_PH(0, 0);
    BAR();
    DS_B(1);
    BAR();
    MFMA_PH(0, 1);
    asm volatile("s_waitcnt vmcnt(0)" ::: "memory");
    BAR();
    DS_A(1);
    BAR();
    MFMA_PH(1, 0);
    BAR();
    MFMA_PH(1, 1);
  }

  // epilogue: +bias, relu, store dense h
  const int ccol = lane & 15;
  const int crow = (lane >> 4) * 4;
#pragma unroll
  for (int j = 0; j < 4; ++j) {
    const int col = tn * 256 + wc * 64 + j * 16 + ccol;
    const float bv = bias[col];
#pragma unroll
    for (int i = 0; i < 8; ++i) {
      const int row0 = tm * 256 + wr * 128 + i * 16 + crow;
#pragma unroll
      for (int p = 0; p < 4; ++p) {
        float v = acc[i][j][p] + bv;
        Hout[(size_t)(row0 + p) * H_HID + col] = fmaxf(v, 0.0f);
      }
    }
  }
#undef DS_A
#undef DS_B
#undef MFMA_PH
#undef STAGE_A
#undef STAGE_B
#undef BAR
}

// ---------------- top-K sparsify (in place) ----------------
#define TK_THREADS 512
#define TK_CAP     512

__global__ __launch_bounds__(TK_THREADS) void topk_kernel(float* __restrict__ latent,
                                                          float* __restrict__ cvals,
                                                          int* __restrict__ cidx) {
  __shared__ float    sh[H_HID];
  __shared__ uint32_t hist[2048];
  __shared__ uint32_t chunkS[TK_THREADS];
  __shared__ uint32_t sh_d, sh_cnt, sh_above;
  __shared__ int      s_special;
  __shared__ int      s_ndef, s_ncand;

  const int tid = threadIdx.x;
  const int row = blockIdx.x;
  float* rowp = latent + (size_t)row * H_HID;

  for (int i = tid; i < H_HID / 4; i += TK_THREADS)
    reinterpret_cast<float4*>(sh)[i] = reinterpret_cast<const float4*>(rowp)[i];
  __syncthreads();

  uint32_t prefix = 0, pmask = 0;
  uint32_t loB = 1, hiB = 1;
  int need = K_TOP;
  int special = 0;

#pragma unroll 1
  for (int level = 0; level < 3; ++level) {
    const int shift = (level == 0) ? 20 : (level == 1) ? 9 : 0;
    const int nbins = (level == 2) ? 512 : 2048;
    for (int b = tid; b < nbins; b += TK_THREADS) hist[b] = 0;
    __syncthreads();
    for (int i4 = tid; i4 < H_HID / 4; i4 += TK_THREADS) {
      float4 v = reinterpret_cast<const float4*>(sh)[i4];
      const float vs[4] = {v.x, v.y, v.z, v.w};
#pragma unroll
      for (int c = 0; c < 4; ++c) {
        uint32_t key = __float_as_uint(vs[c]);
        if (key != 0u && (key & pmask) == prefix)
          atomicAdd(&hist[(key >> shift) & (nbins - 1)], 1u);
      }
    }
    __syncthreads();
    const int cpt = nbins / TK_THREADS;
    uint32_t cs = 0;
#pragma unroll
    for (int c = 0; c < 4; ++c)
      if (c < cpt) cs += hist[tid * cpt + c];
    chunkS[tid] = cs;
    __syncthreads();
    for (int off = 1; off < TK_THREADS; off <<= 1) {
      uint32_t v = (tid + off < TK_THREADS) ? chunkS[tid + off] : 0u;
      __syncthreads();
      chunkS[tid] += v;
      __syncthreads();
    }
    if (level == 0 && tid == 0) s_special = (chunkS[0] <= (uint32_t)K_TOP);
    __syncthreads();
    if (level == 0 && s_special) { special = 1; break; }
    {
      uint32_t cum = (tid + 1 < TK_THREADS) ? chunkS[tid + 1] : 0u;
#pragma unroll
      for (int c = 3; c >= 0; --c) {
        if (c < cpt) {
          const int b = tid * cpt + c;
          const uint32_t nxt = cum;
          cum += hist[b];
          if (cum >= (uint32_t)need && nxt < (uint32_t)need) {
            sh_d = (uint32_t)b; sh_cnt = hist[b]; sh_above = nxt;
          }
        }
      }
    }
    __syncthreads();
    const uint32_t d = sh_d, cnt = sh_cnt, above = sh_above;
    need -= (int)above;
    prefix |= d << shift;
    pmask  |= (uint32_t)(nbins - 1) << shift;
    loB = prefix;
    hiB = prefix + (1u << shift);
    if (cnt <= TK_CAP || level == 2) break;
  }
  const int r = special ? 0 : need;

  float*    cand_val = reinterpret_cast<float*>(hist);
  int*      cand_idx = reinterpret_cast<int*>(hist + 512);
  uint32_t* bitmap   = hist + 1024;
  __syncthreads();
  if (tid < 512) bitmap[tid] = 0u;
  if (tid == 0) { s_ndef = 0; s_ncand = 0; }
  __syncthreads();

  for (int i4 = tid; i4 < H_HID / 4; i4 += TK_THREADS) {
    float4 v = reinterpret_cast<const float4*>(sh)[i4];
    const float vs[4] = {v.x, v.y, v.z, v.w};
#pragma unroll
    for (int c = 0; c < 4; ++c) {
      const uint32_t key = __float_as_uint(vs[c]);
      if (key == 0u) continue;
      const int i = i4 * 4 + c;
      if (key >= hiB) {
        const int p = atomicAdd(&s_ndef, 1);
        cvals[row * K_TOP + p] = vs[c];
        cidx[row * K_TOP + p]  = i;
        atomicOr(&bitmap[i >> 5], 1u << (i & 31));
      } else if (key >= loB) {
        const int p = atomicAdd(&s_ncand, 1);
        if (p < TK_CAP) { cand_val[p] = vs[c]; cand_idx[p] = i; }
      }
    }
  }
  __syncthreads();
  const int ndef = s_ndef, ncand = s_ncand;

  if (r > 0) {
    if (ncand <= TK_CAP) {
      if (tid < ncand) {
        const float vi = cand_val[tid];
        const int   ii = cand_idx[tid];
        int rank = 0;
        for (int j = 0; j < ncand; ++j) {
          const float vj = cand_val[j];
          const int   ij = cand_idx[j];
          rank += (vj > vi) || (vj == vi && ij < ii);
        }
        if (rank < r) {
          cvals[row * K_TOP + ndef + rank] = vi;
          cidx[row * K_TOP + ndef + rank]  = ii;
          atomicOr(&bitmap[ii >> 5], 1u << (ii & 31));
        }
      }
    } else {
      if (tid < 64) {
        int taken = 0;
        for (int base = 0; base < H_HID && taken < r; base += 64) {
          const uint32_t key = __float_as_uint(sh[base + tid]);
          const bool eq = (key >= loB && key < hiB);
          const unsigned long long m = __ballot(eq);
          const int below = __popcll(m & ((1ull << tid) - 1ull));
          if (eq && taken + below < r) {
            const int slot = ndef + taken + below;
            cvals[row * K_TOP + slot] = sh[base + tid];
            cidx[row * K_TOP + slot]  = base + tid;
            atomicOr(&bitmap[(base + tid) >> 5], 1u << ((base + tid) & 31));
          }
          taken += __popcll(m);
        }
      }
    }
  }
  if (tid >= ndef + r && tid < K_TOP) {
    cvals[row * K_TOP + tid] = 0.0f;
    cidx[row * K_TOP + tid]  = 0;
  }
  __syncthreads();

  for (int i4 = tid; i4 < H_HID / 4; i4 += TK_THREADS) {
    float4 v = reinterpret_cast<const float4*>(sh)[i4];
    const int i0 = i4 * 4;
    const uint32_t bm = bitmap[i0 >> 5];
    float4 o;
    o.x = ((bm >> ((i0 + 0) & 31)) & 1u) ? v.x : 0.0f;
    o.y = ((bm >> ((i0 + 1) & 31)) & 1u) ? v.y : 0.0f;
    o.z = ((bm >> ((i0 + 2) & 31)) & 1u) ? v.z : 0.0f;
    o.w = ((bm >> ((i0 + 3) & 31)) & 1u) ? v.w : 0.0f;
    reinterpret_cast<float4*>(rowp)[i4] = o;
  }
}

// ---------------- sparse decoder ----------------
__global__ __launch_bounds__(256) void decode_kernel(const float* __restrict__ cvals,
                                                     const int* __restrict__ cidx,
                                                     const float* __restrict__ Wdec,
                                                     const float* __restrict__ bias,
                                                     float* __restrict__ recon) {
  __shared__ float sv[K_TOP];
  __shared__ int   si[K_TOP];
  const int tid = threadIdx.x;
  const int row = blockIdx.x;
  if (tid < K_TOP) {
    sv[tid] = cvals[row * K_TOP + tid];
    si[tid] = cidx[row * K_TOP + tid];
  }
  __syncthreads();
  const float4 b4 = reinterpret_cast<const float4*>(bias)[tid];
  float ax = b4.x, ay = b4.y, az = b4.z, aw = b4.w;
#pragma unroll 1
  for (int k = 0; k < K_TOP; ++k) {
    const float v = sv[k];
    const float4 w = reinterpret_cast<const float4*>(Wdec + (size_t)si[k] * D_IN)[tid];
    ax = fmaf(v, w.x, ax);
    ay = fmaf(v, w.y, ay);
    az = fmaf(v, w.z, az);
    aw = fmaf(v, w.w, aw);
  }
  reinterpret_cast<float4*>(recon + (size_t)row * D_IN)[tid] = make_float4(ax, ay, az, aw);
}

// ---------------- launch ----------------

extern "C" void kernel_launch(void* const* d_in, const int* in_sizes, int n_in,
                              void* d_out, int out_size, void* d_ws, size_t ws_size,
                              hipStream_t stream) {
  (void)in_sizes; (void)n_in; (void)out_size; (void)ws_size;
  const float* Xv     = (const float*)d_in[0];
  const float* Xt     = (const float*)d_in[1];
  const float* Wv_enc = (const float*)d_in[2];
  const float* bv_enc = (const float*)d_in[3];
  const float* Wt_enc = (const float*)d_in[4];
  const float* bt_enc = (const float*)d_in[5];
  const float* Wv_dec = (const float*)d_in[6];
  const float* bv_dec = (const float*)d_in[7];
  const float* Wt_dec = (const float*)d_in[8];
  const float* bt_dec = (const float*)d_in[9];

  float* out      = (float*)d_out;
  float* recon_v  = out;
  float* recon_t  = out + (size_t)B_ROWS * D_IN;
  float* latent_v = out + 2ull * B_ROWS * D_IN;
  float* latent_t = latent_v + (size_t)B_ROWS * H_HID;

  char* ws = (char*)d_ws;
  const size_t szA = (size_t)B_ROWS * D_IN;
  const size_t szB = (size_t)H_HID * D_IN;
  ushort* Ah_v = (ushort*)ws;
  ushort* Al_v = Ah_v + szA;
  ushort* Ah_t = Al_v + szA;
  ushort* Al_t = Ah_t + szA;
  ushort* Bh_v = Al_t + szA;
  ushort* Bl_v = Bh_v + szB;
  ushort* Bh_t = Bl_v + szB;
  ushort* Bl_t = Bh_t + szB;
  float*  cvals_v = (float*)(Bl_t + szB);
  float*  cvals_t = cvals_v + (size_t)B_ROWS * K_TOP;
  int*    cidx_v  = (int*)(cvals_t + (size_t)B_ROWS * K_TOP);
  int*    cidx_t  = cidx_v + (size_t)B_ROWS * K_TOP;

  // allow 128KB dynamic LDS for the 8-phase GEMM
  hipFuncSetAttribute((const void*)gemm_enc_8ph,
                      hipFuncAttributeMaxDynamicSharedMemorySize, 131072);

  // 1) precision splits
  split_a_kernel<<<B_ROWS * D_IN / 1024, 256, 0, stream>>>(Xv, Ah_v, Al_v);
  split_a_kernel<<<B_ROWS * D_IN / 1024, 256, 0, stream>>>(Xt, Ah_t, Al_t);
  dim3 tg(H_HID / 32, D_IN / 32);
  split_wt_kernel<<<tg, dim3(32, 8), 0, stream>>>(Wv_enc, Bh_v, Bl_v);
  split_wt_kernel<<<tg, dim3(32, 8), 0, stream>>>(Wt_enc, Bh_t, Bl_t);

  // 2) encoder GEMMs (dense h written into latent regions of d_out)
  gemm_enc_8ph<<<(B_ROWS / 256) * (H_HID / 256), 512, 131072, stream>>>(
      Ah_v, Al_v, Bh_v, Bl_v, bv_enc, latent_v);
  gemm_enc_8ph<<<(B_ROWS / 256) * (H_HID / 256), 512, 131072, stream>>>(
      Ah_t, Al_t, Bh_t, Bl_t, bt_enc, latent_t);

  // 3) exact top-32 sparsify in place + compact lists
  topk_kernel<<<B_ROWS, TK_THREADS, 0, stream>>>(latent_v, cvals_v, cidx_v);
  topk_kernel<<<B_ROWS, TK_THREADS, 0, stream>>>(latent_t, cvals_t, cidx_t);

  // 4) sparse decoders
  decode_kernel<<<B_ROWS, 256, 0, stream>>>(cvals_v, cidx_v, Wv_dec, bv_dec, recon_v);
  decode_kernel<<<B_ROWS, 256, 0, stream>>>(cvals_t, cidx_t, Wt_dec, bt_dec, recon_t);
}

// Round 4
// 920.775 us; speedup vs baseline: 2.4611x; 1.4175x over previous
//
#include <hip/hip_runtime.h>
#include <hip/hip_fp16.h>
#include <stdint.h>

#define B_ROWS 4096
#define D_IN   1024
#define H_HID  16384
#define K_TOP  32

typedef __attribute__((ext_vector_type(8))) _Float16 half8;
typedef __attribute__((ext_vector_type(4))) float    f32x4;

// ---------------- helpers ----------------

// f16 hi part; zero if |x| below f16 min-normal (deterministic error bound,
// no dependence on MFMA subnormal-input behavior).
__device__ __forceinline__ ushort hi16(float x) {
  return (fabsf(x) >= 0x1p-14f) ? __half_as_ushort(__float2half(x)) : (ushort)0;
}

__device__ __forceinline__ void gload_lds16(const void* g, void* l) {
  __builtin_amdgcn_global_load_lds(
      (const __attribute__((address_space(1))) void*)g,
      (__attribute__((address_space(3))) void*)l, 16, 0, 0);
}

// ---------------- split kernels ----------------

__global__ __launch_bounds__(256) void split_a_kernel(const float* __restrict__ x,
                                                      ushort* __restrict__ hi) {
  const int t = blockIdx.x * 256 + threadIdx.x;
  const int base = t * 4;
  float4 v = *reinterpret_cast<const float4*>(x + base);
  ushort4 h;
  h.x = hi16(v.x); h.y = hi16(v.y); h.z = hi16(v.z); h.w = hi16(v.w);
  *reinterpret_cast<ushort4*>(hi + base) = h;
}

// W [D_IN, H_HID] f32 -> hiT [H_HID, D_IN] f16 bits + wT32 [H_HID, D_IN] f32
__global__ __launch_bounds__(256) void split_wt_kernel(const float* __restrict__ W,
                                                       ushort* __restrict__ hiT,
                                                       float* __restrict__ wT32) {
  __shared__ float tile[32][33];
  const int c0 = blockIdx.x * 32;
  const int r0 = blockIdx.y * 32;
  const int tx = threadIdx.x;
  const int ty = threadIdx.y;
#pragma unroll
  for (int i = 0; i < 32; i += 8)
    tile[ty + i][tx] = W[(size_t)(r0 + ty + i) * H_HID + c0 + tx];
  __syncthreads();
#pragma unroll
  for (int i = 0; i < 32; i += 8) {
    float v = tile[tx][ty + i];
    size_t o = (size_t)(c0 + ty + i) * D_IN + r0 + tx;
    hiT[o]  = hi16(v);
    wT32[o] = v;
  }
}

// ---------------- encoder GEMM: 256x256 tile, 8-phase pipelined, 1 segment --
// h~ = relu(Ah @ Bh^T + b)  (f16-hi approx; exact refinement happens in topk)
#define NTILES 16   // 1024 / 64

__global__ __launch_bounds__(512, 2) void gemm_enc_8ph(const ushort* __restrict__ Ah,
                                                       const ushort* __restrict__ Bh,
                                                       const float* __restrict__ bias,
                                                       float* __restrict__ Hout) {
  extern __shared__ ushort smem[];   // [2][32768]: buf*32768, B-half at +16384
  const int tid  = threadIdx.x;
  const int wid  = tid >> 6;
  const int lane = tid & 63;
  const int wr   = wid >> 2;
  const int wc   = wid & 3;
  const int tm   = blockIdx.x & 15;
  const int tn   = blockIdx.x >> 4;
  const int rowA0 = tm * 256;
  const int rowB0 = tn * 256;

  const int st_row = wid * 8 + (lane >> 3);
  const int st_lin = lane & 7;
  const int st_src = (lane & 7) ^ ((lane >> 3) & 7);
  const int fr   = lane & 15;
  const int fk   = lane >> 4;
  const int swz8 = (lane & 7) << 3;

  f32x4 acc[8][4];
#pragma unroll
  for (int i = 0; i < 8; ++i)
#pragma unroll
    for (int j = 0; j < 4; ++j) {
      f32x4 z = {0.f, 0.f, 0.f, 0.f};
      acc[i][j] = z;
    }
  half8 a[4][2], b[4][2];

#define DS_A(MH)                                                            \
  _Pragma("unroll") for (int m = 0; m < 4; ++m)                             \
  _Pragma("unroll") for (int k = 0; k < 2; ++k) {                           \
    const int r = wr * 128 + ((MH) * 4 + m) * 16 + fr;                      \
    const int idx = (r * 64 + k * 32 + fk * 8) ^ swz8;                      \
    a[m][k] = *reinterpret_cast<const half8*>(Acur + idx);                  \
  }
#define DS_B(NH)                                                            \
  _Pragma("unroll") for (int n = 0; n < 2; ++n)                             \
  _Pragma("unroll") for (int k = 0; k < 2; ++k) {                           \
    const int r = wc * 64 + ((NH) * 2 + n) * 16 + fr;                       \
    const int idx = (r * 64 + k * 32 + fk * 8) ^ swz8;                      \
    b[(NH) * 2 + n][k] = *reinterpret_cast<const half8*>(Bcur + idx);       \
  }
#define MFMA_PH(MH, NH)                                                     \
  __builtin_amdgcn_s_setprio(1);                                            \
  _Pragma("unroll") for (int m = 0; m < 4; ++m)                             \
  _Pragma("unroll") for (int n = 0; n < 2; ++n)                             \
  _Pragma("unroll") for (int k = 0; k < 2; ++k)                             \
    acc[(MH) * 4 + m][(NH) * 2 + n] = __builtin_amdgcn_mfma_f32_16x16x32_f16( \
        a[m][k], b[(NH) * 2 + n][k], acc[(MH) * 4 + m][(NH) * 2 + n], 0, 0, 0); \
  __builtin_amdgcn_s_setprio(0);
#define STAGE_A(Q)                                                          \
  gload_lds16(Ah + (size_t)(rowA0 + (Q) * 64 + st_row) * 1024 + k0 + st_src * 8, \
              Lnxt + ((Q) * 64 + st_row) * 64 + st_lin * 8)
#define STAGE_B(Q)                                                          \
  gload_lds16(Bh + (size_t)(rowB0 + (Q) * 64 + st_row) * 1024 + k0 + st_src * 8, \
              Lnxt + 16384 + ((Q) * 64 + st_row) * 64 + st_lin * 8)
#define BAR() __builtin_amdgcn_s_barrier()

  // prologue: stage tile 0 into buf0.  Order: Bq0..3, Aq0, Aq2, Aq1, Aq3.
  int k0 = 0;
  ushort* Lnxt = smem;
  STAGE_B(0); STAGE_B(1); STAGE_B(2); STAGE_B(3);
  STAGE_A(0); STAGE_A(2); STAGE_A(1); STAGE_A(3);
  asm volatile("s_waitcnt vmcnt(2)" ::: "memory");
  BAR();

#pragma unroll 1
  for (int t = 0; t < NTILES - 1; ++t) {
    const int cur = t & 1;
    const ushort* Acur = smem + cur * 32768;
    const ushort* Bcur = Acur + 16384;
    Lnxt = smem + (cur ^ 1) * 32768;
    k0 = (t + 1) << 6;

    // phase 1
    DS_A(0); DS_B(0);
    STAGE_B(0); STAGE_B(1);
    BAR();
    MFMA_PH(0, 0);
    BAR();
    // phase 2
    DS_B(1);
    STAGE_B(2); STAGE_B(3);
    BAR();
    MFMA_PH(0, 1);
    asm volatile("s_waitcnt vmcnt(4)" ::: "memory");
    BAR();
    // phase 3
    DS_A(1);
    STAGE_A(0); STAGE_A(2);
    BAR();
    MFMA_PH(1, 0);
    BAR();
    // phase 4
    STAGE_A(1); STAGE_A(3);
    BAR();
    MFMA_PH(1, 1);
    asm volatile("s_waitcnt vmcnt(2)" ::: "memory");
    BAR();
  }

  // epilogue tile (no staging)
  {
    const ushort* Acur = smem + ((NTILES - 1) & 1) * 32768;
    const ushort* Bcur = Acur + 16384;
    DS_A(0); DS_B(0);
    BAR();
    MFMA_PH(0, 0);
    BAR();
    DS_B(1);
    BAR();
    MFMA_PH(0, 1);
    asm volatile("s_waitcnt vmcnt(0)" ::: "memory");
    BAR();
    DS_A(1);
    BAR();
    MFMA_PH(1, 0);
    BAR();
    MFMA_PH(1, 1);
  }

  // epilogue: +bias, relu, store h~
  const int ccol = lane & 15;
  const int crow = (lane >> 4) * 4;
#pragma unroll
  for (int j = 0; j < 4; ++j) {
    const int col = tn * 256 + wc * 64 + j * 16 + ccol;
    const float bv = bias[col];
#pragma unroll
    for (int i = 0; i < 8; ++i) {
      const int row0 = tm * 256 + wr * 128 + i * 16 + crow;
#pragma unroll
      for (int p = 0; p < 4; ++p) {
        float v = acc[i][j][p] + bv;
        Hout[(size_t)(row0 + p) * H_HID + col] = fmaxf(v, 0.0f);
      }
    }
  }
#undef DS_A
#undef DS_B
#undef MFMA_PH
#undef STAGE_A
#undef STAGE_B
#undef BAR
}

// ---------------- top-K sparsify with exact boundary refinement ----------------
// One block (512 thr) per row.  3-level radix -> exact 32nd-largest T of h~.
// Elements > T+DELTA are provably in the true top-32 (|h~-h| << DELTA);
// elements < T-DELTA provably out; the window [T-DELTA, T+DELTA] (~3 elems)
// is refined EXACTLY via f64 dot(x_row, W_col)+bias and ranked
// (value desc, index asc) = jax.lax.top_k tie-break.
#define TK_THREADS 512
#define WCAP       256
#define TK_DELTA   6e-3f

__global__ __launch_bounds__(TK_THREADS) void topk_kernel(float* __restrict__ latent,
                                                          float* __restrict__ cvals,
                                                          int* __restrict__ cidx,
                                                          const float* __restrict__ X,
                                                          const float* __restrict__ WT,
                                                          const float* __restrict__ bias) {
  __shared__ float    sh[H_HID];        // 64 KB
  __shared__ uint32_t hist[2048];       // 8 KB; reused: bitmap[512]|wval[256]|widx[256]
  __shared__ double   wexact[WCAP];     // 2 KB
  __shared__ uint32_t chunkS[TK_THREADS];
  __shared__ uint32_t sh_d;
  __shared__ int      s_special, s_ndef, s_nw;

  const int tid = threadIdx.x;
  const int row = blockIdx.x;
  float* rowp = latent + (size_t)row * H_HID;

  for (int i = tid; i < H_HID / 4; i += TK_THREADS)
    reinterpret_cast<float4*>(sh)[i] = reinterpret_cast<const float4*>(rowp)[i];
  __syncthreads();

  // ---- 3-level radix: exact 32nd-largest positive (all 31 value bits) ----
  uint32_t prefix = 0, pmask = 0;
  int need = K_TOP;
  int special = 0;
#pragma unroll 1
  for (int level = 0; level < 3; ++level) {
    const int shift = (level == 0) ? 20 : (level == 1) ? 9 : 0;
    const int nbins = (level == 2) ? 512 : 2048;
    for (int bb = tid; bb < nbins; bb += TK_THREADS) hist[bb] = 0;
    __syncthreads();
    for (int i4 = tid; i4 < H_HID / 4; i4 += TK_THREADS) {
      float4 v = reinterpret_cast<const float4*>(sh)[i4];
      const float vs[4] = {v.x, v.y, v.z, v.w};
#pragma unroll
      for (int c = 0; c < 4; ++c) {
        uint32_t key = __float_as_uint(vs[c]);
        if (key != 0u && (key & pmask) == prefix)
          atomicAdd(&hist[(key >> shift) & (nbins - 1)], 1u);
      }
    }
    __syncthreads();
    const int cpt = nbins / TK_THREADS;   // 4,4,1
    uint32_t cs = 0;
#pragma unroll
    for (int c = 0; c < 4; ++c)
      if (c < cpt) cs += hist[tid * cpt + c];
    chunkS[tid] = cs;
    __syncthreads();
    for (int off = 1; off < TK_THREADS; off <<= 1) {
      uint32_t v = (tid + off < TK_THREADS) ? chunkS[tid + off] : 0u;
      __syncthreads();
      chunkS[tid] += v;
      __syncthreads();
    }
    if (level == 0 && tid == 0) s_special = (chunkS[0] <= (uint32_t)K_TOP);
    __syncthreads();
    if (level == 0 && s_special) { special = 1; break; }
    {
      uint32_t cum = (tid + 1 < TK_THREADS) ? chunkS[tid + 1] : 0u;
      uint32_t dd = 0, ab = 0;
      bool found = false;
#pragma unroll
      for (int c = 3; c >= 0; --c) {
        if (c < cpt) {
          const int bb = tid * cpt + c;
          const uint32_t nxt = cum;
          cum += hist[bb];
          if (cum >= (uint32_t)need && nxt < (uint32_t)need) {
            dd = (uint32_t)bb; ab = nxt; found = true;
          }
        }
      }
      if (found) { sh_d = (dd << 8) | 0u; chunkS[0] = ab; sh_d = dd; }
      __syncthreads();
      if (found) chunkS[1] = ab;   // stash 'above' (single writer)
      __syncthreads();
      const uint32_t d = sh_d, above = chunkS[1];
      need -= (int)above;
      prefix |= d << shift;
      pmask  |= (uint32_t)(nbins - 1) << shift;
    }
    __syncthreads();
  }

  const float Tt = __uint_as_float(prefix);
  const float Tp = special ? 0.0f : (Tt + TK_DELTA);
  const float Tm = special ? 3.0e38f : fmaxf(Tt - TK_DELTA, 0.0f);

  // ---- reuse hist: bitmap[0..511], wval[512..767], widx[768..1023] ----
  uint32_t* bitmap = hist;
  float*    wval   = reinterpret_cast<float*>(hist + 512);
  int*      widx   = reinterpret_cast<int*>(hist + 768);
  __syncthreads();
  if (tid < 512) bitmap[tid] = 0u;
  if (tid == 0) { s_ndef = 0; s_nw = 0; }
  __syncthreads();

  // ---- classify: definite / window ----
  for (int i4 = tid; i4 < H_HID / 4; i4 += TK_THREADS) {
    float4 v = reinterpret_cast<const float4*>(sh)[i4];
    const float vs[4] = {v.x, v.y, v.z, v.w};
#pragma unroll
    for (int c = 0; c < 4; ++c) {
      const float x = vs[c];
      if (x <= 0.0f) continue;
      const int i = i4 * 4 + c;
      if (x > Tp) {
        const int p = atomicAdd(&s_ndef, 1);
        cvals[row * K_TOP + p] = x;
        cidx[row * K_TOP + p]  = i;
        atomicOr(&bitmap[i >> 5], 1u << (i & 31));
      } else if (x >= Tm) {
        const int p = atomicAdd(&s_nw, 1);
        if (p < WCAP) { wval[p] = x; widx[p] = i; }
      }
    }
  }
  __syncthreads();
  const int ndef = s_ndef;
  const int nww  = (s_nw < WCAP) ? s_nw : WCAP;
  const int r    = special ? 0 : (K_TOP - ndef);

  if (r > 0) {
    // ---- exact refinement: one wave per window candidate ----
    const int wv = tid >> 6, lane = tid & 63;
    const float* xr = X + (size_t)row * D_IN;
    for (int c = wv; c < nww; c += 8) {
      const float* wr = WT + (size_t)widx[c] * D_IN;
      double a = 0.0;
#pragma unroll
      for (int j = 0; j < 16; ++j)
        a += (double)xr[lane + 64 * j] * (double)wr[lane + 64 * j];
#pragma unroll
      for (int off = 32; off; off >>= 1) a += __shfl_xor(a, off);
      if (lane == 0) wexact[c] = a + (double)bias[widx[c]];
    }
    __syncthreads();
    // ---- rank window by (exact desc, index asc); take top r ----
    if (tid < nww) {
      const double ei = wexact[tid];
      const int    ii = widx[tid];
      int rank = 0;
      for (int j = 0; j < nww; ++j) {
        const double ej = wexact[j];
        const int    ij = widx[j];
        rank += (ej > ei) || (ej == ei && ij < ii);
      }
      if (rank < r) {
        cvals[row * K_TOP + ndef + rank] = wval[tid];
        cidx[row * K_TOP + ndef + rank]  = ii;
        atomicOr(&bitmap[ii >> 5], 1u << (ii & 31));
      }
    }
  }
  // pad (only when <32 positives)
  if (tid >= ndef + r && tid < K_TOP) {
    cvals[row * K_TOP + tid] = 0.0f;
    cidx[row * K_TOP + tid]  = 0;
  }
  __syncthreads();

  // ---- write back: keep selected, zero the rest ----
  for (int i4 = tid; i4 < H_HID / 4; i4 += TK_THREADS) {
    float4 v = reinterpret_cast<const float4*>(sh)[i4];
    const int i0 = i4 * 4;
    const uint32_t bm = bitmap[i0 >> 5];
    float4 o;
    o.x = ((bm >> ((i0 + 0) & 31)) & 1u) ? v.x : 0.0f;
    o.y = ((bm >> ((i0 + 1) & 31)) & 1u) ? v.y : 0.0f;
    o.z = ((bm >> ((i0 + 2) & 31)) & 1u) ? v.z : 0.0f;
    o.w = ((bm >> ((i0 + 3) & 31)) & 1u) ? v.w : 0.0f;
    reinterpret_cast<float4*>(rowp)[i4] = o;
  }
}

// ---------------- sparse decoder ----------------
__global__ __launch_bounds__(256) void decode_kernel(const float* __restrict__ cvals,
                                                     const int* __restrict__ cidx,
                                                     const float* __restrict__ Wdec,
                                                     const float* __restrict__ bias,
                                                     float* __restrict__ recon) {
  __shared__ float sv[K_TOP];
  __shared__ int   si[K_TOP];
  const int tid = threadIdx.x;
  const int row = blockIdx.x;
  if (tid < K_TOP) {
    sv[tid] = cvals[row * K_TOP + tid];
    si[tid] = cidx[row * K_TOP + tid];
  }
  __syncthreads();
  const float4 b4 = reinterpret_cast<const float4*>(bias)[tid];
  float ax = b4.x, ay = b4.y, az = b4.z, aw = b4.w;
#pragma unroll 1
  for (int k = 0; k < K_TOP; ++k) {
    const float v = sv[k];
    const float4 w = reinterpret_cast<const float4*>(Wdec + (size_t)si[k] * D_IN)[tid];
    ax = fmaf(v, w.x, ax);
    ay = fmaf(v, w.y, ay);
    az = fmaf(v, w.z, az);
    aw = fmaf(v, w.w, aw);
  }
  reinterpret_cast<float4*>(recon + (size_t)row * D_IN)[tid] = make_float4(ax, ay, az, aw);
}

// ---------------- launch ----------------

extern "C" void kernel_launch(void* const* d_in, const int* in_sizes, int n_in,
                              void* d_out, int out_size, void* d_ws, size_t ws_size,
                              hipStream_t stream) {
  (void)in_sizes; (void)n_in; (void)out_size; (void)ws_size;
  const float* Xv     = (const float*)d_in[0];
  const float* Xt     = (const float*)d_in[1];
  const float* Wv_enc = (const float*)d_in[2];
  const float* bv_enc = (const float*)d_in[3];
  const float* Wt_enc = (const float*)d_in[4];
  const float* bt_enc = (const float*)d_in[5];
  const float* Wv_dec = (const float*)d_in[6];
  const float* bv_dec = (const float*)d_in[7];
  const float* Wt_dec = (const float*)d_in[8];
  const float* bt_dec = (const float*)d_in[9];

  float* out      = (float*)d_out;
  float* recon_v  = out;
  float* recon_t  = out + (size_t)B_ROWS * D_IN;
  float* latent_v = out + 2ull * B_ROWS * D_IN;
  float* latent_t = latent_v + (size_t)B_ROWS * H_HID;

  char* ws = (char*)d_ws;
  const size_t szA = (size_t)B_ROWS * D_IN;
  const size_t szB = (size_t)H_HID * D_IN;
  ushort* Ah_v = (ushort*)ws;
  ushort* Ah_t = Ah_v + szA;
  ushort* Bh_v = Ah_t + szA;
  ushort* Bh_t = Bh_v + szB;
  float*  WT32_t = (float*)(Bh_t + szB);          // 64 MB in ws
  float*  cvals_v = WT32_t + szB;
  float*  cvals_t = cvals_v + (size_t)B_ROWS * K_TOP;
  int*    cidx_v  = (int*)(cvals_t + (size_t)B_ROWS * K_TOP);
  int*    cidx_t  = cidx_v + (size_t)B_ROWS * K_TOP;
  // v-stream exact W^T parks in the latent_t OUTPUT region: it is consumed by
  // topk(v) strictly before gemm(t) overwrites latent_t.
  float*  WT32_v = latent_t;

  hipFuncSetAttribute((const void*)gemm_enc_8ph,
                      hipFuncAttributeMaxDynamicSharedMemorySize, 131072);

  // splits
  split_a_kernel<<<B_ROWS * D_IN / 1024, 256, 0, stream>>>(Xv, Ah_v);
  split_a_kernel<<<B_ROWS * D_IN / 1024, 256, 0, stream>>>(Xt, Ah_t);
  dim3 tg(H_HID / 32, D_IN / 32);
  split_wt_kernel<<<tg, dim3(32, 8), 0, stream>>>(Wv_enc, Bh_v, WT32_v);
  split_wt_kernel<<<tg, dim3(32, 8), 0, stream>>>(Wt_enc, Bh_t, WT32_t);

  // vision stream
  gemm_enc_8ph<<<(B_ROWS / 256) * (H_HID / 256), 512, 131072, stream>>>(
      Ah_v, Bh_v, bv_enc, latent_v);
  topk_kernel<<<B_ROWS, TK_THREADS, 0, stream>>>(latent_v, cvals_v, cidx_v,
                                                 Xv, WT32_v, bv_enc);
  decode_kernel<<<B_ROWS, 256, 0, stream>>>(cvals_v, cidx_v, Wv_dec, bv_dec, recon_v);

  // text stream (gemm overwrites WT32_v's region -> already consumed)
  gemm_enc_8ph<<<(B_ROWS / 256) * (H_HID / 256), 512, 131072, stream>>>(
      Ah_t, Bh_t, bt_enc, latent_t);
  topk_kernel<<<B_ROWS, TK_THREADS, 0, stream>>>(latent_t, cvals_t, cidx_t,
                                                 Xt, WT32_t, bt_enc);
  decode_kernel<<<B_ROWS, 256, 0, stream>>>(cvals_t, cidx_t, Wt_dec, bt_dec, recon_t);
}

// Round 5
// 816.856 us; speedup vs baseline: 2.7742x; 1.1272x over previous
//
#include <hip/hip_runtime.h>
#include <hip/hip_fp16.h>
#include <stdint.h>

#define B_ROWS 4096
#define D_IN   1024
#define H_HID  16384
#define K_TOP  32

typedef __attribute__((ext_vector_type(8))) _Float16 half8;
typedef __attribute__((ext_vector_type(4))) float    f32x4;

// ---------------- helpers ----------------

// f16 hi part; zero if |x| below f16 min-normal (deterministic error bound).
__device__ __forceinline__ ushort hi16(float x) {
  return (fabsf(x) >= 0x1p-14f) ? __half_as_ushort(__float2half(x)) : (ushort)0;
}

__device__ __forceinline__ float h16_to_f32(uint32_t key) {
  union { ushort u; __half h; } cv;
  cv.u = (ushort)key;
  return __half2float(cv.h);
}

__device__ __forceinline__ void gload_lds16(const void* g, void* l) {
  __builtin_amdgcn_global_load_lds(
      (const __attribute__((address_space(1))) void*)g,
      (__attribute__((address_space(3))) void*)l, 16, 0, 0);
}

// ---------------- split kernels ----------------

__global__ __launch_bounds__(256) void split_a_kernel(const float* __restrict__ x,
                                                      ushort* __restrict__ hi) {
  const int t = blockIdx.x * 256 + threadIdx.x;
  const int base = t * 4;
  float4 v = *reinterpret_cast<const float4*>(x + base);
  ushort4 h;
  h.x = hi16(v.x); h.y = hi16(v.y); h.z = hi16(v.z); h.w = hi16(v.w);
  *reinterpret_cast<ushort4*>(hi + base) = h;
}

// W [D_IN, H_HID] f32 -> hiT [H_HID, D_IN] f16 bits + wT32 [H_HID, D_IN] f32
__global__ __launch_bounds__(256) void split_wt_kernel(const float* __restrict__ W,
                                                       ushort* __restrict__ hiT,
                                                       float* __restrict__ wT32) {
  __shared__ float tile[32][33];
  const int c0 = blockIdx.x * 32;
  const int r0 = blockIdx.y * 32;
  const int tx = threadIdx.x;
  const int ty = threadIdx.y;
#pragma unroll
  for (int i = 0; i < 32; i += 8)
    tile[ty + i][tx] = W[(size_t)(r0 + ty + i) * H_HID + c0 + tx];
  __syncthreads();
#pragma unroll
  for (int i = 0; i < 32; i += 8) {
    float v = tile[tx][ty + i];
    size_t o = (size_t)(c0 + ty + i) * D_IN + r0 + tx;
    hiT[o]  = hi16(v);
    wT32[o] = v;
  }
}

// ---------------- encoder GEMM: 256x256 tile, 8-phase pipelined, 1 segment --
// h~ = relu(Ah @ Bh^T + b), stored as f16 to workspace (selection exactness is
// restored by the refinement window in topk; f16 store error ~4e-4).
#define NTILES 16   // 1024 / 64

__global__ __launch_bounds__(512, 2) void gemm_enc_8ph(const ushort* __restrict__ Ah,
                                                       const ushort* __restrict__ Bh,
                                                       const float* __restrict__ bias,
                                                       ushort* __restrict__ Hout) {
  extern __shared__ ushort smem[];   // [2][32768]: buf*32768, B-half at +16384
  const int tid  = threadIdx.x;
  const int wid  = tid >> 6;
  const int lane = tid & 63;
  const int wr   = wid >> 2;
  const int wc   = wid & 3;
  const int tm   = blockIdx.x & 15;
  const int tn   = blockIdx.x >> 4;
  const int rowA0 = tm * 256;
  const int rowB0 = tn * 256;

  const int st_row = wid * 8 + (lane >> 3);
  const int st_lin = lane & 7;
  const int st_src = (lane & 7) ^ ((lane >> 3) & 7);
  const int fr   = lane & 15;
  const int fk   = lane >> 4;
  const int swz8 = (lane & 7) << 3;

  f32x4 acc[8][4];
#pragma unroll
  for (int i = 0; i < 8; ++i)
#pragma unroll
    for (int j = 0; j < 4; ++j) {
      f32x4 z = {0.f, 0.f, 0.f, 0.f};
      acc[i][j] = z;
    }
  half8 a[4][2], b[4][2];

#define DS_A(MH)                                                            \
  _Pragma("unroll") for (int m = 0; m < 4; ++m)                             \
  _Pragma("unroll") for (int k = 0; k < 2; ++k) {                           \
    const int r = wr * 128 + ((MH) * 4 + m) * 16 + fr;                      \
    const int idx = (r * 64 + k * 32 + fk * 8) ^ swz8;                      \
    a[m][k] = *reinterpret_cast<const half8*>(Acur + idx);                  \
  }
#define DS_B(NH)                                                            \
  _Pragma("unroll") for (int n = 0; n < 2; ++n)                             \
  _Pragma("unroll") for (int k = 0; k < 2; ++k) {                           \
    const int r = wc * 64 + ((NH) * 2 + n) * 16 + fr;                       \
    const int idx = (r * 64 + k * 32 + fk * 8) ^ swz8;                      \
    b[(NH) * 2 + n][k] = *reinterpret_cast<const half8*>(Bcur + idx);       \
  }
#define MFMA_PH(MH, NH)                                                     \
  __builtin_amdgcn_s_setprio(1);                                            \
  _Pragma("unroll") for (int m = 0; m < 4; ++m)                             \
  _Pragma("unroll") for (int n = 0; n < 2; ++n)                             \
  _Pragma("unroll") for (int k = 0; k < 2; ++k)                             \
    acc[(MH) * 4 + m][(NH) * 2 + n] = __builtin_amdgcn_mfma_f32_16x16x32_f16( \
        a[m][k], b[(NH) * 2 + n][k], acc[(MH) * 4 + m][(NH) * 2 + n], 0, 0, 0); \
  __builtin_amdgcn_s_setprio(0);
#define STAGE_A(Q)                                                          \
  gload_lds16(Ah + (size_t)(rowA0 + (Q) * 64 + st_row) * 1024 + k0 + st_src * 8, \
              Lnxt + ((Q) * 64 + st_row) * 64 + st_lin * 8)
#define STAGE_B(Q)                                                          \
  gload_lds16(Bh + (size_t)(rowB0 + (Q) * 64 + st_row) * 1024 + k0 + st_src * 8, \
              Lnxt + 16384 + ((Q) * 64 + st_row) * 64 + st_lin * 8)
#define BAR() __builtin_amdgcn_s_barrier()

  // prologue: stage tile 0 into buf0.  Order: Bq0..3, Aq0, Aq2, Aq1, Aq3.
  int k0 = 0;
  ushort* Lnxt = smem;
  STAGE_B(0); STAGE_B(1); STAGE_B(2); STAGE_B(3);
  STAGE_A(0); STAGE_A(2); STAGE_A(1); STAGE_A(3);
  asm volatile("s_waitcnt vmcnt(2)" ::: "memory");
  BAR();

#pragma unroll 1
  for (int t = 0; t < NTILES - 1; ++t) {
    const int cur = t & 1;
    const ushort* Acur = smem + cur * 32768;
    const ushort* Bcur = Acur + 16384;
    Lnxt = smem + (cur ^ 1) * 32768;
    k0 = (t + 1) << 6;

    // phase 1
    DS_A(0); DS_B(0);
    STAGE_B(0); STAGE_B(1);
    BAR();
    MFMA_PH(0, 0);
    BAR();
    // phase 2
    DS_B(1);
    STAGE_B(2); STAGE_B(3);
    BAR();
    MFMA_PH(0, 1);
    asm volatile("s_waitcnt vmcnt(4)" ::: "memory");
    BAR();
    // phase 3
    DS_A(1);
    STAGE_A(0); STAGE_A(2);
    BAR();
    MFMA_PH(1, 0);
    BAR();
    // phase 4
    STAGE_A(1); STAGE_A(3);
    BAR();
    MFMA_PH(1, 1);
    asm volatile("s_waitcnt vmcnt(2)" ::: "memory");
    BAR();
  }

  // epilogue tile (no staging)
  {
    const ushort* Acur = smem + ((NTILES - 1) & 1) * 32768;
    const ushort* Bcur = Acur + 16384;
    DS_A(0); DS_B(0);
    BAR();
    MFMA_PH(0, 0);
    BAR();
    DS_B(1);
    BAR();
    MFMA_PH(0, 1);
    asm volatile("s_waitcnt vmcnt(0)" ::: "memory");
    BAR();
    DS_A(1);
    BAR();
    MFMA_PH(1, 0);
    BAR();
    MFMA_PH(1, 1);
  }

  // epilogue: +bias, relu, store h~ as f16
  const int ccol = lane & 15;
  const int crow = (lane >> 4) * 4;
#pragma unroll
  for (int j = 0; j < 4; ++j) {
    const int col = tn * 256 + wc * 64 + j * 16 + ccol;
    const float bv = bias[col];
#pragma unroll
    for (int i = 0; i < 8; ++i) {
      const int row0 = tm * 256 + wr * 128 + i * 16 + crow;
#pragma unroll
      for (int p = 0; p < 4; ++p) {
        float v = fmaxf(acc[i][j][p] + bv, 0.0f);
        Hout[(size_t)(row0 + p) * H_HID + col] = __half_as_ushort(__float2half(v));
      }
    }
  }
#undef DS_A
#undef DS_B
#undef MFMA_PH
#undef STAGE_A
#undef STAGE_B
#undef BAR
}

// ---------------- top-K select (f16 keys) + exact refinement + dense write ----
// One block (512 thr) per row.  2-level radix on u16 keys (bits[15:5] then
// [4:0]) -> exact 32nd-largest T~ of h~16.  v > T+D definite (provably in true
// top-32), v in [T-D, T+D] refined exactly via f64 dot(x, Wcol)+bias, ranked
// (value desc, index asc) = jax tie-break.  Dense f32 latent is WRITE-ONLY.
#define TK_THREADS 512
#define WCAP       256
#define TK_DELTA   1e-2f

__global__ __launch_bounds__(TK_THREADS) void topk16_kernel(
    const ushort* __restrict__ H16,
    float* __restrict__ latent,
    float* __restrict__ cvals, int* __restrict__ cidx,
    const float* __restrict__ X, const float* __restrict__ WT,
    const float* __restrict__ bias) {
  __shared__ ushort   sh[H_HID];        // 32 KB
  __shared__ uint32_t hist[2048];       // 8 KB; reused: bitmap|wval|widx
  __shared__ uint32_t chunkS[TK_THREADS];
  __shared__ double   wexact[WCAP];
  __shared__ uint32_t s_d0, s_above, s_d1;
  __shared__ int      s_special, s_ndef, s_nw;

  const int tid = threadIdx.x;
  const int row = blockIdx.x;
  const ushort* rowp16 = H16 + (size_t)row * H_HID;

  for (int i = tid; i < H_HID / 8; i += TK_THREADS)
    reinterpret_cast<uint4*>(sh)[i] = reinterpret_cast<const uint4*>(rowp16)[i];

  // ---- level 0: 2048 bins = key >> 5 ----
#pragma unroll
  for (int c = 0; c < 4; ++c) hist[tid + c * TK_THREADS] = 0;
  __syncthreads();
  for (int i8 = tid; i8 < H_HID / 8; i8 += TK_THREADS) {
    uint4 u = reinterpret_cast<const uint4*>(sh)[i8];
    const uint32_t wsv[4] = {u.x, u.y, u.z, u.w};
#pragma unroll
    for (int c = 0; c < 4; ++c) {
#pragma unroll
      for (int hh = 0; hh < 2; ++hh) {
        const uint32_t key = (wsv[c] >> (16 * hh)) & 0xffffu;
        if (key) atomicAdd(&hist[key >> 5], 1u);
      }
    }
  }
  __syncthreads();
  uint32_t cs = 0;
#pragma unroll
  for (int c = 0; c < 4; ++c) cs += hist[tid * 4 + c];
  chunkS[tid] = cs;
  __syncthreads();
  for (int off = 1; off < TK_THREADS; off <<= 1) {
    uint32_t v = (tid + off < TK_THREADS) ? chunkS[tid + off] : 0u;
    __syncthreads();
    chunkS[tid] += v;
    __syncthreads();
  }
  if (tid == 0) s_special = (chunkS[0] <= (uint32_t)K_TOP);
  __syncthreads();
  const int special = s_special;
  uint32_t T16 = 0;

  if (!special) {
    uint32_t cum = (tid + 1 < TK_THREADS) ? chunkS[tid + 1] : 0u;
#pragma unroll
    for (int c = 3; c >= 0; --c) {
      const int bb = tid * 4 + c;
      const uint32_t nxt = cum;
      cum += hist[bb];
      if (cum >= (uint32_t)K_TOP && nxt < (uint32_t)K_TOP) {
        s_d0 = (uint32_t)bb; s_above = nxt;
      }
    }
    __syncthreads();
    const uint32_t d0 = s_d0;
    const uint32_t need2 = (uint32_t)K_TOP - s_above;
    // ---- level 1: 32 bins = key & 31 within bin d0 ----
    if (tid < 32) hist[tid] = 0;
    __syncthreads();
    for (int i8 = tid; i8 < H_HID / 8; i8 += TK_THREADS) {
      uint4 u = reinterpret_cast<const uint4*>(sh)[i8];
      const uint32_t wsv[4] = {u.x, u.y, u.z, u.w};
#pragma unroll
      for (int c = 0; c < 4; ++c) {
#pragma unroll
        for (int hh = 0; hh < 2; ++hh) {
          const uint32_t key = (wsv[c] >> (16 * hh)) & 0xffffu;
          if (key && (key >> 5) == d0) atomicAdd(&hist[key & 31], 1u);
        }
      }
    }
    __syncthreads();
    if (tid < 32) {
      uint32_t s = 0;
      for (int b = 31; b >= (int)tid; --b) s += hist[b];
      if (s >= need2 && (s - hist[tid]) < need2) s_d1 = (uint32_t)tid;
    }
    __syncthreads();
    T16 = (s_d0 << 5) | s_d1;
  }

  const float Tt = special ? 0.0f : h16_to_f32(T16);
  const float Tp = special ? 0.0f : (Tt + TK_DELTA);
  const float Tm = special ? 3.0e38f : (Tt - TK_DELTA);

  // ---- reuse hist: bitmap[0..511], wval[512..767], widx[768..1023] ----
  uint32_t* bitmap = hist;
  float*    wval   = reinterpret_cast<float*>(hist + 512);
  int*      widx   = reinterpret_cast<int*>(hist + 768);
  __syncthreads();
  bitmap[tid] = 0u;          // TK_THREADS=512 covers all words
  if (tid == 0) { s_ndef = 0; s_nw = 0; }
  __syncthreads();

  // ---- classify: definite / window ----
  for (int i8 = tid; i8 < H_HID / 8; i8 += TK_THREADS) {
    uint4 u = reinterpret_cast<const uint4*>(sh)[i8];
    const uint32_t wsv[4] = {u.x, u.y, u.z, u.w};
#pragma unroll
    for (int c = 0; c < 4; ++c) {
#pragma unroll
      for (int hh = 0; hh < 2; ++hh) {
        const uint32_t key = (wsv[c] >> (16 * hh)) & 0xffffu;
        if (!key) continue;
        const float v = h16_to_f32(key);
        const int i = i8 * 8 + c * 2 + hh;
        if (v > Tp) {
          const int p = atomicAdd(&s_ndef, 1);
          cvals[row * K_TOP + p] = v;
          cidx[row * K_TOP + p]  = i;
          atomicOr(&bitmap[i >> 5], 1u << (i & 31));
        } else if (v >= Tm) {
          const int p = atomicAdd(&s_nw, 1);
          if (p < WCAP) { wval[p] = v; widx[p] = i; }
        }
      }
    }
  }
  __syncthreads();
  const int ndef = s_ndef;
  const int nww  = (s_nw < WCAP) ? s_nw : WCAP;
  const int r    = special ? 0 : (K_TOP - ndef);

  if (r > 0) {
    // exact refinement: one wave per window candidate, f64 dot
    const int wv = tid >> 6, lane = tid & 63;
    const float* xr = X + (size_t)row * D_IN;
    for (int c = wv; c < nww; c += 8) {
      const float* wr = WT + (size_t)widx[c] * D_IN;
      double a = 0.0;
#pragma unroll
      for (int j = 0; j < 16; ++j)
        a += (double)xr[lane + 64 * j] * (double)wr[lane + 64 * j];
#pragma unroll
      for (int off = 32; off; off >>= 1) a += __shfl_xor(a, off);
      if (lane == 0) wexact[c] = a + (double)bias[widx[c]];
    }
    __syncthreads();
    if (tid < nww) {
      const double ei = wexact[tid];
      const int    ii = widx[tid];
      int rank = 0;
      for (int j = 0; j < nww; ++j) {
        const double ej = wexact[j];
        const int    ij = widx[j];
        rank += (ej > ei) || (ej == ei && ij < ii);
      }
      if (rank < r) {
        cvals[row * K_TOP + ndef + rank] = wval[tid];
        cidx[row * K_TOP + ndef + rank]  = ii;
        atomicOr(&bitmap[ii >> 5], 1u << (ii & 31));
      }
    }
  }
  if (tid >= ndef + r && tid < K_TOP) {
    cvals[row * K_TOP + tid] = 0.0f;
    cidx[row * K_TOP + tid]  = 0;
  }
  __syncthreads();

  // ---- dense f32 latent: pure write (zeros + selected) ----
  float* rowp = latent + (size_t)row * H_HID;
  for (int i4 = tid; i4 < H_HID / 4; i4 += TK_THREADS) {
    const uint2 u = reinterpret_cast<const uint2*>(sh)[i4];
    const uint32_t k0 = u.x & 0xffffu, k1 = u.x >> 16;
    const uint32_t k2 = u.y & 0xffffu, k3 = u.y >> 16;
    const int i0 = i4 * 4;
    const uint32_t bm = bitmap[i4 >> 3];
    float4 o;
    o.x = ((bm >> ((i0 + 0) & 31)) & 1u) ? h16_to_f32(k0) : 0.0f;
    o.y = ((bm >> ((i0 + 1) & 31)) & 1u) ? h16_to_f32(k1) : 0.0f;
    o.z = ((bm >> ((i0 + 2) & 31)) & 1u) ? h16_to_f32(k2) : 0.0f;
    o.w = ((bm >> ((i0 + 3) & 31)) & 1u) ? h16_to_f32(k3) : 0.0f;
    reinterpret_cast<float4*>(rowp)[i4] = o;
  }
}

// ---------------- sparse decoder ----------------
__global__ __launch_bounds__(256) void decode_kernel(const float* __restrict__ cvals,
                                                     const int* __restrict__ cidx,
                                                     const float* __restrict__ Wdec,
                                                     const float* __restrict__ bias,
                                                     float* __restrict__ recon) {
  __shared__ float sv[K_TOP];
  __shared__ int   si[K_TOP];
  const int tid = threadIdx.x;
  const int row = blockIdx.x;
  if (tid < K_TOP) {
    sv[tid] = cvals[row * K_TOP + tid];
    si[tid] = cidx[row * K_TOP + tid];
  }
  __syncthreads();
  const float4 b4 = reinterpret_cast<const float4*>(bias)[tid];
  float ax = b4.x, ay = b4.y, az = b4.z, aw = b4.w;
#pragma unroll 1
  for (int k = 0; k < K_TOP; ++k) {
    const float v = sv[k];
    const float4 w = reinterpret_cast<const float4*>(Wdec + (size_t)si[k] * D_IN)[tid];
    ax = fmaf(v, w.x, ax);
    ay = fmaf(v, w.y, ay);
    az = fmaf(v, w.z, az);
    aw = fmaf(v, w.w, aw);
  }
  reinterpret_cast<float4*>(recon + (size_t)row * D_IN)[tid] = make_float4(ax, ay, az, aw);
}

// ---------------- launch ----------------

extern "C" void kernel_launch(void* const* d_in, const int* in_sizes, int n_in,
                              void* d_out, int out_size, void* d_ws, size_t ws_size,
                              hipStream_t stream) {
  (void)in_sizes; (void)n_in; (void)out_size; (void)ws_size;
  const float* Xv     = (const float*)d_in[0];
  const float* Xt     = (const float*)d_in[1];
  const float* Wv_enc = (const float*)d_in[2];
  const float* bv_enc = (const float*)d_in[3];
  const float* Wt_enc = (const float*)d_in[4];
  const float* bt_enc = (const float*)d_in[5];
  const float* Wv_dec = (const float*)d_in[6];
  const float* bv_dec = (const float*)d_in[7];
  const float* Wt_dec = (const float*)d_in[8];
  const float* bt_dec = (const float*)d_in[9];

  float* out      = (float*)d_out;
  float* recon_v  = out;
  float* recon_t  = out + (size_t)B_ROWS * D_IN;
  float* latent_v = out + 2ull * B_ROWS * D_IN;
  float* latent_t = latent_v + (size_t)B_ROWS * H_HID;

  char* ws = (char*)d_ws;
  const size_t szA = (size_t)B_ROWS * D_IN;    // 4M
  const size_t szB = (size_t)H_HID * D_IN;     // 16M
  const size_t szH = (size_t)B_ROWS * H_HID;   // 64M
  ushort* Ah_v  = (ushort*)ws;
  ushort* Ah_t  = Ah_v + szA;
  ushort* Bh_v  = Ah_t + szA;
  ushort* Bh_t  = Bh_v + szB;
  ushort* H16_v = Bh_t + szB;
  ushort* H16_t = H16_v + szH;
  float*  WT32_v = (float*)(H16_t + szH);
  float*  WT32_t = WT32_v + szB;
  float*  cvals_v = WT32_t + szB;
  float*  cvals_t = cvals_v + (size_t)B_ROWS * K_TOP;
  int*    cidx_v  = (int*)(cvals_t + (size_t)B_ROWS * K_TOP);
  int*    cidx_t  = cidx_v + (size_t)B_ROWS * K_TOP;

  hipFuncSetAttribute((const void*)gemm_enc_8ph,
                      hipFuncAttributeMaxDynamicSharedMemorySize, 131072);

  // splits
  split_a_kernel<<<B_ROWS * D_IN / 1024, 256, 0, stream>>>(Xv, Ah_v);
  split_a_kernel<<<B_ROWS * D_IN / 1024, 256, 0, stream>>>(Xt, Ah_t);
  dim3 tg(H_HID / 32, D_IN / 32);
  split_wt_kernel<<<tg, dim3(32, 8), 0, stream>>>(Wv_enc, Bh_v, WT32_v);
  split_wt_kernel<<<tg, dim3(32, 8), 0, stream>>>(Wt_enc, Bh_t, WT32_t);

  // vision stream
  gemm_enc_8ph<<<(B_ROWS / 256) * (H_HID / 256), 512, 131072, stream>>>(
      Ah_v, Bh_v, bv_enc, H16_v);
  topk16_kernel<<<B_ROWS, TK_THREADS, 0, stream>>>(H16_v, latent_v, cvals_v, cidx_v,
                                                   Xv, WT32_v, bv_enc);
  decode_kernel<<<B_ROWS, 256, 0, stream>>>(cvals_v, cidx_v, Wv_dec, bv_dec, recon_v);

  // text stream
  gemm_enc_8ph<<<(B_ROWS / 256) * (H_HID / 256), 512, 131072, stream>>>(
      Ah_t, Bh_t, bt_enc, H16_t);
  topk16_kernel<<<B_ROWS, TK_THREADS, 0, stream>>>(H16_t, latent_t, cvals_t, cidx_t,
                                                   Xt, WT32_t, bt_enc);
  decode_kernel<<<B_ROWS, 256, 0, stream>>>(cvals_t, cidx_t, Wt_dec, bt_dec, recon_t);
}